// Round 11
// baseline (458.268 us; speedup 1.0000x reference)
//
#include <hip/hip_runtime.h>
#include <hip/hip_bf16.h>
#include <math.h>

typedef __bf16 bf16x8 __attribute__((ext_vector_type(8)));
typedef __bf16 bf16x4 __attribute__((ext_vector_type(4)));
typedef float f32x4 __attribute__((ext_vector_type(4)));

#define MFMA16(a,b,c) __builtin_amdgcn_mfma_f32_16x16x32_bf16(a,b,c,0,0,0)

static constexpr int Nn = 48, Hh = 256;
static constexpr int Ee = 2256, BT = 64;
static constexpr int ETILE = 64, NTILES = 36;          // 36*64 = 2304 >= 2256
static constexpr float BN_RS = 0.9999950000374998f;    // 1/sqrt(1+1e-5)

// ---- ws layout (bytes) ----
static constexpr size_t WS_WF  = 0;         // 4 mats frag-linear + mf1 frags: 557056
static constexpr size_t WS_RRA = 557056;    // 36*2*3*64*8 bf16 = 221184
static constexpr size_t WS_TN  = 778240;    // 268320 f32 = 1073280
static constexpr size_t WS_AGG = 1851520;   // g_agg [64][48][256] f32 = 3145728 (MODE0)
static constexpr size_t WS_PB  = 4997248;   // bf16 partials [256][48][256] = 6291456 (MODE1)
static constexpr size_t WS_NEED1 = WS_PB + 6291456;  // 11288704

// ---- LDS layout (bytes), total 77056 ----
static constexpr int LDS_ACT = 0;        // [64][512B] swizzled act (fc1 out / at1_l1 out)
static constexpr int LDS_ALM = 32768;    // [64][512B] all_msgs act, then h_edges B-frags
static constexpr int LDS_PMA = 65536;    // [64][64B] pre_msg bf16, K=32 padded (k=8 const 1.0)
static constexpr int LDS_RT  = 69632;    // [64][2] f32
static constexpr int LDS_BS  = 70144;    // 1536 f32 biases
static constexpr int LDS_XS  = 76288;    // 192 f32
static constexpr int LDS_EDGE_BYTES = 77056;

__device__ __forceinline__ float eluf(float v) { return v > 0.f ? v : __expf(v) - 1.f; }

__device__ __forceinline__ int aoff(int e, int colbyte) {
  return e * 512 + (colbyte ^ ((e & 7) << 4));
}

// One N-pass of the K=256 GEMM: 64 edges (4 m-tiles) x 16 cols (1 n-tile).
// A from swizzled LDS; B frag-linear in GLOBAL -> registers (L2-hot, 16B/lane,
// 1-deep prefetch). NO barriers. acc[4] = 16 regs; worst-point live
// ~= ag24 + acc16 + Bcur8 + Bnext8 + af16 + addr ~= 90 < 128 (r9: 135, r10: ~130
// both spilled at the 128 cap -> N-split to 2 sequential passes).
__device__ __forceinline__ void gemm256n1(const char* smem_act, const char* wmat,
                                          int ncol, int lane, f32x4 acc[4]) {
  const int kgb = (lane >> 4) * 16;
  const int c16 = lane & 15;
  const int sx = (c16 & 7) << 4;
  const char* wbase = wmat + ((size_t)(ncol * 64 + lane)) * 16;
  bf16x8 b = *(const bf16x8*)(wbase);
#pragma unroll
  for (int kt = 0; kt < 8; ++kt) {
    bf16x8 cb = b;
    if (kt < 7) b = *(const bf16x8*)(wbase + (kt + 1) * 16384);
    const int kx = (kt * 64 + kgb) ^ sx;
#pragma unroll
    for (int mt = 0; mt < 4; ++mt) {
      bf16x8 af = *(const bf16x8*)(smem_act + (mt * 16 + c16) * 512 + kx);
      acc[mt] = MFMA16(af, cb, acc[mt]);
    }
  }
}

template<int MODE>
__global__ __launch_bounds__(512)
void edge_kernel(const float* __restrict__ x, const float* __restrict__ rel_rec,
                 const float* __restrict__ rel_send, const float* __restrict__ rel_type,
                 const float* __restrict__ mf2_b, const float* __restrict__ at1_b1,
                 const float* __restrict__ at1_b2, const float* __restrict__ at1_g,
                 const float* __restrict__ at1_be, const __bf16* __restrict__ wf,
                 const __bf16* __restrict__ rra, float* __restrict__ g_agg,
                 __bf16* __restrict__ partb) {
  extern __shared__ char smem[];
  float* xs = (float*)(smem + LDS_XS);
  float* rt = (float*)(smem + LDS_RT);
  float* bs = (float*)(smem + LDS_BS);
  const char* wfb = (const char*)wf;

  const int tid = threadIdx.x;
  const int lane = tid & 63;
  const int wv = tid >> 6;
  const int lg = lane >> 4;
  const int col16 = lane & 15;
  const int n0 = wv * 32;                 // this wave's 32 output cols
  const int slice = blockIdx.x >> 2;
  const int split = blockIdx.x & 3;
  const int t_begin = split * 9;

  // block-start preloads: xs, bias table, PMA zero+ones
  if (tid < Nn * 4) xs[tid] = x[slice * Nn * 4 + tid];
#pragma unroll
  for (int i = 0; i < 3; ++i) {
    int t = i * 512 + tid, which = t >> 8, o = t & 255;
    float v;
    switch (which) {
      case 0: v = mf2_b[o]; break;
      case 1: v = mf2_b[256 + o]; break;
      case 2: v = at1_b1[o]; break;
      case 3: v = at1_b2[o]; break;
      case 4: v = at1_g[o] * BN_RS; break;
      default: v = at1_be[o]; break;
    }
    bs[t] = v;
  }
#pragma unroll
  for (int t = tid; t < 1024; t += 512)   // grid-stride: 1024 uints, 512 threads
    ((unsigned int*)(smem + LDS_PMA))[t] = ((t & 15) == 4) ? 0x00003f80u : 0u;

  f32x4 ag[3][2];
#pragma unroll
  for (int a = 0; a < 3; ++a)
#pragma unroll
    for (int b = 0; b < 2; ++b) ag[a][b] = (f32x4){0.f, 0.f, 0.f, 0.f};
  __syncthreads();

  for (int tt = 0; tt < 9; ++tt) {
    const int tile = t_begin + tt;
    const int e0 = tile * ETILE;
    const int ne = (Ee - e0 < ETILE) ? (Ee - e0) : ETILE;

    // rel_type tile
    if (tid < ETILE * 2) {
      int e = tid >> 1, i2 = tid & 1;
      rt[tid] = (e < ne) ? rel_type[((size_t)slice * Ee + e0 + e) * 2 + i2] : 0.f;
    }
    // pre_msg -> PMA bf16 (k-cols 0..7; col 8 stays 1.0 for bias)
    {
      int c = tid >> 6, e = tid & 63;
      float s = 0.f;
      if (e < ne) {
        const float* rel = ((c < 4) ? rel_send : rel_rec) + (size_t)(e0 + e) * Nn;
        int f = c & 3;
#pragma unroll
        for (int n = 0; n < Nn; ++n) s += rel[n] * xs[n * 4 + f];
      }
      *(__bf16*)(smem + LDS_PMA + e * 64 + c * 2) = (__bf16)s;
    }
    __syncthreads();  // B1: PMA + rt visible

    // per-edge-type: fc1 (MFMA, bias folded) -> mf2 GEMM -> relu*rt accum in ALM
#pragma unroll 1
    for (int ty = 0; ty < 2; ++ty) {
      {
        // fc1: A = PMA [64][32], B = mf1 frags from global (2 x 16B/lane)
        const char* src = wfb + 524288 + ty * 16384 + ((size_t)(wv * 2 * 64 + lane)) * 16;
        bf16x8 wb0 = *(const bf16x8*)(src);
        bf16x8 wb1 = *(const bf16x8*)(src + 1024);
        f32x4 fa[4][2];
#pragma unroll
        for (int mt = 0; mt < 4; ++mt)
#pragma unroll
          for (int nt = 0; nt < 2; ++nt) fa[mt][nt] = (f32x4){0.f, 0.f, 0.f, 0.f};
#pragma unroll
        for (int mt = 0; mt < 4; ++mt) {
          bf16x8 af = *(const bf16x8*)(smem + LDS_PMA + (mt * 16 + col16) * 64 + lg * 16);
          fa[mt][0] = MFMA16(af, wb0, fa[mt][0]);
          fa[mt][1] = MFMA16(af, wb1, fa[mt][1]);
        }
        // relu -> ACT (swizzled act layout)
#pragma unroll
        for (int mt = 0; mt < 4; ++mt)
#pragma unroll
          for (int nt = 0; nt < 2; ++nt) {
            int cb = (n0 + nt * 16 + col16) * 2;
#pragma unroll
            for (int r = 0; r < 4; ++r) {
              int e = mt * 16 + lg * 4 + r;
              *(__bf16*)(smem + LDS_ACT + aoff(e, cb)) = (__bf16)fmaxf(fa[mt][nt][r], 0.f);
            }
          }
      }
      __syncthreads();  // B2/B4: ACT visible (and prev ACT readers done)

      // mf2[ty] in two sequential N-passes (register budget)
#pragma unroll 1
      for (int nt = 0; nt < 2; ++nt) {
        f32x4 acc[4];
#pragma unroll
        for (int mt = 0; mt < 4; ++mt) acc[mt] = (f32x4){0.f, 0.f, 0.f, 0.f};
        gemm256n1(smem + LDS_ACT, wfb + (size_t)ty * 131072, wv * 2 + nt, lane, acc);
        const float bbv = bs[ty * 256 + n0 + nt * 16 + col16];
        const int cb = (n0 + nt * 16 + col16) * 2;
#pragma unroll
        for (int mt = 0; mt < 4; ++mt) {
#pragma unroll
          for (int r = 0; r < 4; ++r) {
            int e = mt * 16 + lg * 4 + r;
            float v = fmaxf(acc[mt][r] + bbv, 0.f) * rt[e * 2 + ty];
            __bf16* p = (__bf16*)(smem + LDS_ALM + aoff(e, cb));
            if (ty == 1) v += (float)*p;  // own patch: same thread wrote it at ty=0
            *p = (__bf16)v;
          }
        }
      }
      __syncthreads();  // B3/B5: ACT reads done (ty0) / ALM visible (ty1)
    }

    // at1_l1: ALM @ W -> elu -> ACT  (two N-passes)
#pragma unroll 1
    for (int nt = 0; nt < 2; ++nt) {
      f32x4 acc[4];
#pragma unroll
      for (int mt = 0; mt < 4; ++mt) acc[mt] = (f32x4){0.f, 0.f, 0.f, 0.f};
      gemm256n1(smem + LDS_ALM, wfb + (size_t)2 * 131072, wv * 2 + nt, lane, acc);
      const float bbv = bs[512 + n0 + nt * 16 + col16];
      const int cb = (n0 + nt * 16 + col16) * 2;
#pragma unroll
      for (int mt = 0; mt < 4; ++mt)
#pragma unroll
        for (int r = 0; r < 4; ++r) {
          int e = mt * 16 + lg * 4 + r;
          *(__bf16*)(smem + LDS_ACT + aoff(e, cb)) = (__bf16)eluf(acc[mt][r] + bbv);
        }
    }
    __syncthreads();  // B6: ACT(elu) visible; ALM reads done before B-frag overwrite

    // at1_l2: ACT @ W -> elu*sc+be -> h_edges B-frags in ALM  (two N-passes)
#pragma unroll 1
    for (int nt = 0; nt < 2; ++nt) {
      f32x4 acc[4];
#pragma unroll
      for (int mt = 0; mt < 4; ++mt) acc[mt] = (f32x4){0.f, 0.f, 0.f, 0.f};
      gemm256n1(smem + LDS_ACT, wfb + (size_t)3 * 131072, wv * 2 + nt, lane, acc);
      const int col = n0 + nt * 16 + col16;
      const float b_ = bs[768 + col], s1 = bs[1024 + col], s2 = bs[1280 + col];
      const int j0 = (lg & 1) * 4;
#pragma unroll
      for (int mt = 0; mt < 4; ++mt) {
        const int ktile = mt >> 1;
        const int lane2 = col16 | (((2 * mt + (lg >> 1)) & 3) << 4);
        bf16x4 pk;
#pragma unroll
        for (int r = 0; r < 4; ++r)
          pk[r] = (__bf16)(eluf(acc[mt][r] + b_) * s1 + s2);
        int addr = (((ktile * 16 + wv * 2 + nt) * 64 + lane2) * 8 + j0) * 2;
        *(bf16x4*)(smem + LDS_ALM + addr) = pk;
      }
    }
    __syncthreads();  // B7: B-frags visible

    // agg GEMM: ag += rel_rec[tile]^T @ h_edges  (M=48, N=256, K=64)
    const bf16x8* rraw = (const bf16x8*)rra + (size_t)tile * 384;
#pragma unroll
    for (int kt2 = 0; kt2 < 2; ++kt2) {
      bf16x8 b0 = *(const bf16x8*)(smem + LDS_ALM + ((kt2 * 16 + wv * 2 + 0) * 64 + lane) * 16);
      bf16x8 b1 = *(const bf16x8*)(smem + LDS_ALM + ((kt2 * 16 + wv * 2 + 1) * 64 + lane) * 16);
#pragma unroll
      for (int mt2 = 0; mt2 < 3; ++mt2) {
        bf16x8 a = rraw[(kt2 * 3 + mt2) * 64 + lane];
        ag[mt2][0] = MFMA16(a, b0, ag[mt2][0]);
        ag[mt2][1] = MFMA16(a, b1, ag[mt2][1]);
      }
    }
    // next tile's first ALM/ACT writes are >=2 barriers away -> safe
  }

  if (MODE == 1) {
    __bf16* dst = partb + (size_t)blockIdx.x * Nn * Hh;
#pragma unroll
    for (int mt2 = 0; mt2 < 3; ++mt2)
#pragma unroll
      for (int ntl = 0; ntl < 2; ++ntl) {
        int h = (wv * 2 + ntl) * 16 + col16;
#pragma unroll
        for (int r = 0; r < 4; ++r) {
          int n = mt2 * 16 + lg * 4 + r;
          dst[n * Hh + h] = (__bf16)ag[mt2][ntl][r];
        }
      }
  } else {
    float* dst = g_agg + (size_t)slice * Nn * Hh;
#pragma unroll
    for (int mt2 = 0; mt2 < 3; ++mt2)
#pragma unroll
      for (int ntl = 0; ntl < 2; ++ntl) {
        int h = (wv * 2 + ntl) * 16 + col16;
#pragma unroll
        for (int r = 0; r < 4; ++r) {
          int n = mt2 * 16 + lg * 4 + r;
          atomicAdd(dst + n * Hh + h, ag[mt2][ntl][r]);
        }
      }
  }
}

// 4 weight matrices [256][256] fp32 -> bf16 MFMA B-fragment-linear
__global__ void prep_frag(const float* __restrict__ mf2_w, const float* __restrict__ at1_w1,
                          const float* __restrict__ at1_w2, __bf16* __restrict__ wfdst) {
  int id = blockIdx.x * 256 + threadIdx.x;  // 32768 total
  int mat = id >> 13, r = id & 8191;
  int kt = r >> 10, q = r & 1023, nt = q >> 6, l = q & 63;
  int row = nt * 16 + (l & 15), col = kt * 32 + (l >> 4) * 8;
  const float* src = (mat == 0) ? mf2_w : (mat == 1) ? (mf2_w + 65536)
                   : (mat == 2) ? at1_w1 : at1_w2;
  const float* p = src + row * 256 + col;
  __bf16* d = wfdst + (size_t)mat * 65536 + ((size_t)(kt * 16 + nt) * 64 + l) * 8;
#pragma unroll
  for (int j = 0; j < 8; ++j) d[j] = (__bf16)p[j];
}

// mf1 (2F=8 -> H=256) as K=32-padded B-frags; bias folded at k=8
__global__ void prep_mf1(const float* __restrict__ mf1_w, const float* __restrict__ mf1_b,
                         __bf16* __restrict__ wfdst) {
  int id = blockIdx.x * 256 + threadIdx.x;  // 2048 total
  int ty = id >> 10, q = id & 1023, ntg = q >> 6, l = q & 63;
  int col = ntg * 16 + (l & 15);
  int k0 = (l >> 4) * 8;
  bf16x8 v;
#pragma unroll
  for (int j = 0; j < 8; ++j) {
    int k = k0 + j;
    float x = (k < 8) ? mf1_w[ty * 2048 + col * 8 + k]
            : (k == 8) ? mf1_b[ty * 256 + col] : 0.f;
    v[j] = (__bf16)x;
  }
  ((bf16x8*)(wfdst + 262144))[id] = v;
}

// rel_rec^T per-tile bf16 A-fragments: rra[tile][kt2(2)][mt2(3)][lane][8]
__global__ void prep_rra(const float* __restrict__ rel_rec, __bf16* __restrict__ rra) {
  int id = blockIdx.x * 256 + threadIdx.x;  // 36*384 = 13824
  if (id >= 13824) return;
  int tile = id / 384, r = id % 384;
  int kt2 = r / 192, r2 = r % 192, mt2 = r2 >> 6, l = r2 & 63;
  int ebase = tile * 64 + kt2 * 32 + (l >> 4) * 8;
  int n = mt2 * 16 + (l & 15);
  bf16x8 v;
#pragma unroll
  for (int j = 0; j < 8; ++j) {
    int e = ebase + j;
    v[j] = (__bf16)((e < Ee) ? rel_rec[(size_t)e * Nn + n] : 0.f);
  }
  ((bf16x8*)rra)[id] = v;
}

// transpose node-side weights (fp32) for coalesced lane reads
__global__ void prep_node(const float* __restrict__ at5_w1, const float* __restrict__ at5_w2,
                          const float* __restrict__ o1_w, const float* __restrict__ o2_w,
                          const float* __restrict__ o3_w, float* __restrict__ ws) {
  int id = blockIdx.x * 256 + threadIdx.x;
  float* T1 = ws;
  float* T2 = T1 + 67600;
  float* To1 = T2 + 67600;
  float* To2 = To1 + 66560;
  float* To3 = To2 + 65536;
  if (id < 67600) { int o = id % 260, k = id / 260; T1[k * 260 + o] = at5_w1[o * 260 + k]; return; }
  id -= 67600;
  if (id < 67600) { int o = id % 260, k = id / 260; T2[k * 260 + o] = at5_w2[o * 260 + k]; return; }
  id -= 67600;
  if (id < 66560) { int o = id & 255, k = id >> 8; To1[k * 256 + o] = o1_w[o * 260 + k]; return; }
  id -= 66560;
  if (id < 65536) { int o = id & 255, k = id >> 8; To2[k * 256 + o] = o2_w[o * 256 + k]; return; }
  id -= 65536;
  if (id < 1024) { int f = id & 3, k = id >> 2; To3[k * 4 + f] = o3_w[f * 256 + k]; }
}

// 512 blocks x 6 node-rows each
template<int MODE>
__global__ __launch_bounds__(256, 4)
void node_kernel(const float* __restrict__ g_agg, const __bf16* __restrict__ partb,
                 const float* __restrict__ x,
                 const float* __restrict__ T1, const float* __restrict__ T2,
                 const float* __restrict__ To1, const float* __restrict__ To2,
                 const float* __restrict__ To3, const float* __restrict__ at5_b1,
                 const float* __restrict__ at5_b2, const float* __restrict__ at5_g,
                 const float* __restrict__ at5_be, const float* __restrict__ o1_b,
                 const float* __restrict__ o2_b, const float* __restrict__ o3_b,
                 float* __restrict__ out) {
  __shared__ float bufA[6 * 264], bufB[6 * 264], xres[6 * 4];
  const int tid = threadIdx.x;
  const int slice = blockIdx.x >> 3, rg = blockIdx.x & 7;
  const int n0 = rg * 6;
  for (int t = tid; t < 6 * 256; t += 256) {
    int r = t >> 8, h = t & 255;
    float s;
    if (MODE == 1) {
      s = 0.f;
#pragma unroll
      for (int sp = 0; sp < 4; ++sp)
        s += (float)partb[((((size_t)slice * 4 + sp) * Nn) + n0 + r) * Hh + h];
    } else {
      s = g_agg[(size_t)slice * 12288 + (size_t)(n0 + r) * 256 + h];
    }
    bufA[r * 264 + h] = s;
  }
  if (tid < 24) {
    int r = tid >> 2, f = tid & 3;
    float v = x[(size_t)slice * 192 + (n0 + r) * 4 + f];
    bufA[r * 264 + 256 + f] = v;
    xres[tid] = v;
  }
  __syncthreads();

  auto layer = [&](const float* WT, const float* bsrc, const float* in, float* outb,
                   int K, int O, int act, const float* gsc, const float* gbe) {
    for (int o = tid; o < O; o += 256) {
      float a[6];
      float bb = bsrc[o];
#pragma unroll
      for (int r = 0; r < 6; ++r) a[r] = bb;
      for (int k = 0; k < K; ++k) {
        float w = WT[k * O + o];
#pragma unroll
        for (int r = 0; r < 6; ++r) a[r] = fmaf(in[r * 264 + k], w, a[r]);
      }
      float scv = 1.f, bev = 0.f;
      if (act == 2) { scv = gsc[o] * BN_RS; bev = gbe[o]; }
#pragma unroll
      for (int r = 0; r < 6; ++r) {
        float v = a[r];
        v = (act == 0) ? fmaxf(v, 0.f) : eluf(v);
        if (act == 2) v = v * scv + bev;
        outb[r * 264 + o] = v;
      }
    }
    __syncthreads();
  };

  layer(T1, at5_b1, bufA, bufB, 260, 260, 1, nullptr, nullptr);
  layer(T2, at5_b2, bufB, bufA, 260, 260, 2, at5_g, at5_be);
  layer(To1, o1_b, bufA, bufB, 260, 256, 0, nullptr, nullptr);
  layer(To2, o2_b, bufB, bufA, 256, 256, 0, nullptr, nullptr);
  if (tid < 24) {
    int r = tid >> 2, f = tid & 3;
    float s = o3_b[f];
    for (int k = 0; k < 256; ++k) s = fmaf(bufA[r * 264 + k], To3[k * 4 + f], s);
    out[(size_t)slice * 192 + (n0 + r) * 4 + f] = xres[tid] + s;
  }
}

extern "C" void kernel_launch(void* const* d_in, const int* in_sizes, int n_in,
                              void* d_out, int out_size, void* d_ws, size_t ws_size,
                              hipStream_t stream) {
  const float* x = (const float*)d_in[0];
  const float* rel_rec = (const float*)d_in[1];
  const float* rel_send = (const float*)d_in[2];
  const float* rel_type = (const float*)d_in[3];
  const float* mf1_w = (const float*)d_in[4];
  const float* mf1_b = (const float*)d_in[5];
  const float* mf2_w = (const float*)d_in[6];
  const float* mf2_b = (const float*)d_in[7];
  const float* at1_w1 = (const float*)d_in[8];
  const float* at1_b1 = (const float*)d_in[9];
  const float* at1_w2 = (const float*)d_in[10];
  const float* at1_b2 = (const float*)d_in[11];
  const float* at1_g = (const float*)d_in[12];
  const float* at1_be = (const float*)d_in[13];
  const float* at5_w1 = (const float*)d_in[14];
  const float* at5_b1 = (const float*)d_in[15];
  const float* at5_w2 = (const float*)d_in[16];
  const float* at5_b2 = (const float*)d_in[17];
  const float* at5_g = (const float*)d_in[18];
  const float* at5_be = (const float*)d_in[19];
  const float* o1_w = (const float*)d_in[20];
  const float* o1_b = (const float*)d_in[21];
  const float* o2_w = (const float*)d_in[22];
  const float* o2_b = (const float*)d_in[23];
  const float* o3_w = (const float*)d_in[24];
  const float* o3_b = (const float*)d_in[25];

  char* ws = (char*)d_ws;
  __bf16* wf = (__bf16*)(ws + WS_WF);
  __bf16* rra = (__bf16*)(ws + WS_RRA);
  float* tnode = (float*)(ws + WS_TN);
  float* g_agg = (float*)(ws + WS_AGG);
  __bf16* partb = (__bf16*)(ws + WS_PB);

  const int mode = (ws_size >= WS_NEED1) ? 1 : 0;

  prep_frag<<<128, 256, 0, stream>>>(mf2_w, at1_w1, at1_w2, wf);
  prep_mf1<<<8, 256, 0, stream>>>(mf1_w, mf1_b, wf);
  prep_rra<<<54, 256, 0, stream>>>(rel_rec, rra);
  prep_node<<<1049, 256, 0, stream>>>(at5_w1, at5_w2, o1_w, o2_w, o3_w, tnode);

  if (mode == 1) {
    hipFuncSetAttribute((const void*)edge_kernel<1>,
                        hipFuncAttributeMaxDynamicSharedMemorySize, LDS_EDGE_BYTES);
    edge_kernel<1><<<BT * 4, 512, LDS_EDGE_BYTES, stream>>>(
        x, rel_rec, rel_send, rel_type, mf2_b, at1_b1, at1_b2,
        at1_g, at1_be, wf, rra, g_agg, partb);
    node_kernel<1><<<512, 256, 0, stream>>>(g_agg, partb, x, tnode, tnode + 67600,
                                            tnode + 135200, tnode + 201760, tnode + 267296,
                                            at5_b1, at5_b2, at5_g, at5_be,
                                            o1_b, o2_b, o3_b, (float*)d_out);
  } else {
    hipMemsetAsync(g_agg, 0, (size_t)BT * Nn * Hh * 4, stream);
    hipFuncSetAttribute((const void*)edge_kernel<0>,
                        hipFuncAttributeMaxDynamicSharedMemorySize, LDS_EDGE_BYTES);
    edge_kernel<0><<<BT * 4, 512, LDS_EDGE_BYTES, stream>>>(
        x, rel_rec, rel_send, rel_type, mf2_b, at1_b1, at1_b2,
        at1_g, at1_be, wf, rra, g_agg, partb);
    node_kernel<0><<<512, 256, 0, stream>>>(g_agg, partb, x, tnode, tnode + 67600,
                                            tnode + 135200, tnode + 201760, tnode + 267296,
                                            at5_b1, at5_b2, at5_g, at5_be,
                                            o1_b, o2_b, o3_b, (float*)d_out);
  }
}

// Round 12
// 318.125 us; speedup vs baseline: 1.4405x; 1.4405x over previous
//
#include <hip/hip_runtime.h>
#include <hip/hip_bf16.h>
#include <math.h>

typedef __bf16 bf16x8 __attribute__((ext_vector_type(8)));
typedef __bf16 bf16x4 __attribute__((ext_vector_type(4)));
typedef float f32x4 __attribute__((ext_vector_type(4)));

#define MFMA16(a,b,c) __builtin_amdgcn_mfma_f32_16x16x32_bf16(a,b,c,0,0,0)

static constexpr int Nn = 48, Hh = 256;
static constexpr int Ee = 2256, BT = 64;
static constexpr int ETILE = 64, NTILES = 36;          // 36*64 = 2304 >= 2256
static constexpr float BN_RS = 0.9999950000374998f;    // 1/sqrt(1+1e-5)

// ---- ws layout (bytes) ----
static constexpr size_t WS_WF  = 0;         // 4 mats frag-linear + mf1 frags: 557056
static constexpr size_t WS_RRA = 557056;    // 36*2*3*64*8 bf16 = 221184
static constexpr size_t WS_TN  = 778240;    // 268320 f32 = 1073280
static constexpr size_t WS_AGG = 1851520;   // g_agg [64][48][256] f32 = 3145728 (MODE0)
static constexpr size_t WS_PB  = 4997248;   // bf16 partials [256][48][256] = 6291456 (MODE1)
static constexpr size_t WS_NEED1 = WS_PB + 6291456;  // 11288704

// ---- LDS layout (bytes), total 142592; 1 block/CU, 16 waves = 4/SIMD ----
static constexpr int LDS_ACT = 0;        // [64][512B] swizzled act
static constexpr int LDS_ALM = 32768;    // [64][512B] all_msgs act, then h_edges B-frags
static constexpr int LDS_WSG = 65536;    // 2 x 32KB double-buffered weight chunk (DMA dest)
static constexpr int LDS_PMA = 131072;   // [64][64B] pre_msg bf16, K=32 padded (k=8 const 1.0)
static constexpr int LDS_RT  = 135168;   // [64][2] f32
static constexpr int LDS_BS  = 135680;   // 1536 f32 biases
static constexpr int LDS_XS  = 141824;   // 192 f32
static constexpr int LDS_EDGE_BYTES = 142592;

__device__ __forceinline__ float eluf(float v) { return v > 0.f ? v : __expf(v) - 1.f; }

typedef __attribute__((address_space(1))) const unsigned int as1_uint;
typedef __attribute__((address_space(3))) unsigned int as3_uint;
__device__ __forceinline__ void gload16(const void* g, void* l) {
  __builtin_amdgcn_global_load_lds((as1_uint*)g, (as3_uint*)l, 16, 0, 0);
}

__device__ __forceinline__ int aoff(int e, int colbyte) {
  return e * 512 + (colbyte ^ ((e & 7) << 4));
}

// K=256 GEMM, 16-wave split: each wave 64 edges (4 m-tiles) x 16 cols (1 n-tile).
// A from swizzled LDS at abase; B frag-linear in global, DMA double-buffered in
// 32KB (K=64) chunks, 1 barrier per chunk. acc[4]=16 regs; live ~80 << 128
// (round-8 no-spill structure; rounds 9-11's register-B variants all spilled).
__device__ __forceinline__ void gemm256d(char* smem, const char* wsrcb, int abase,
                                         int lane, int wv, f32x4 acc[4]) {
  char* wsg = smem + LDS_WSG;
  const int so = wv * 2048 + lane * 16;
  gload16(wsrcb + so, wsg + wv * 2048);
  gload16(wsrcb + so + 1024, wsg + wv * 2048 + 1024);
  __syncthreads();  // chunk0 landed; also covers pre-GEMM LDS writes by all waves
  const int kgb = (lane >> 4) * 16;
  const int c16 = lane & 15;
#pragma unroll
  for (int c = 0; c < 4; ++c) {
    const char* bb = wsg + (c & 1) * 32768;
    if (c < 3) {
      char* nb = wsg + ((c + 1) & 1) * 32768;
      gload16(wsrcb + (c + 1) * 32768 + so, nb + wv * 2048);
      gload16(wsrcb + (c + 1) * 32768 + so + 1024, nb + wv * 2048 + 1024);
    }
#pragma unroll
    for (int ks = 0; ks < 2; ++ks) {
      const int kt = c * 2 + ks;
      bf16x8 bfr = *(const bf16x8*)(bb + ((ks * 16 + wv) * 64 + lane) * 16);
#pragma unroll
      for (int mt = 0; mt < 4; ++mt) {
        int r = mt * 16 + c16;
        bf16x8 af = *(const bf16x8*)(smem + abase + r * 512 + ((kt * 64 + kgb) ^ ((r & 7) << 4)));
        acc[mt] = MFMA16(af, bfr, acc[mt]);
      }
    }
    __syncthreads();  // next chunk landed; current buf free
  }
}

template<int MODE>
__global__ __launch_bounds__(1024)
void edge_kernel(const float* __restrict__ x, const float* __restrict__ rel_rec,
                 const float* __restrict__ rel_send, const float* __restrict__ rel_type,
                 const float* __restrict__ mf2_b, const float* __restrict__ at1_b1,
                 const float* __restrict__ at1_b2, const float* __restrict__ at1_g,
                 const float* __restrict__ at1_be, const __bf16* __restrict__ wf,
                 const __bf16* __restrict__ rra, float* __restrict__ g_agg,
                 __bf16* __restrict__ partb) {
  extern __shared__ char smem[];
  float* xs = (float*)(smem + LDS_XS);
  float* rt = (float*)(smem + LDS_RT);
  float* bs = (float*)(smem + LDS_BS);
  const char* wfb = (const char*)wf;

  const int tid = threadIdx.x;
  const int lane = tid & 63;
  const int wv = tid >> 6;                // 0..15
  const int lg = lane >> 4;
  const int col16 = lane & 15;
  const int slice = blockIdx.x >> 2;
  const int split = blockIdx.x & 3;
  const int t_begin = split * 9;

  // block-start preloads: xs, bias table, PMA zero+ones
  if (tid < Nn * 4) xs[tid] = x[slice * Nn * 4 + tid];
#pragma unroll
  for (int i = 0; i < 2; ++i) {
    int t = i * 1024 + tid;
    if (t < 1536) {
      int which = t >> 8, o = t & 255;
      float v;
      switch (which) {
        case 0: v = mf2_b[o]; break;
        case 1: v = mf2_b[256 + o]; break;
        case 2: v = at1_b1[o]; break;
        case 3: v = at1_b2[o]; break;
        case 4: v = at1_g[o] * BN_RS; break;
        default: v = at1_be[o]; break;
      }
      bs[t] = v;
    }
  }
  // PMA: zeros, with bf16 1.0 at k=8 of each row (1024 uints, 1024 threads)
  ((unsigned int*)(smem + LDS_PMA))[tid] = ((tid & 15) == 4) ? 0x00003f80u : 0u;

  f32x4 ag[3];
#pragma unroll
  for (int a = 0; a < 3; ++a) ag[a] = (f32x4){0.f, 0.f, 0.f, 0.f};
  __syncthreads();

  for (int tt = 0; tt < 9; ++tt) {
    const int tile = t_begin + tt;
    const int e0 = tile * ETILE;
    const int ne = (Ee - e0 < ETILE) ? (Ee - e0) : ETILE;

    // rel_type tile
    if (tid < ETILE * 2) {
      int e = tid >> 1, i2 = tid & 1;
      rt[tid] = (e < ne) ? rel_type[((size_t)slice * Ee + e0 + e) * 2 + i2] : 0.f;
    }
    // pre_msg -> PMA bf16 (k-cols 0..7; col 8 stays 1.0 for bias)
    if (tid < 512) {
      int c = tid >> 6, e = tid & 63;
      float s = 0.f;
      if (e < ne) {
        const float* rel = ((c < 4) ? rel_send : rel_rec) + (size_t)(e0 + e) * Nn;
        int f = c & 3;
#pragma unroll
        for (int n = 0; n < Nn; ++n) s += rel[n] * xs[n * 4 + f];
      }
      *(__bf16*)(smem + LDS_PMA + e * 64 + c * 2) = (__bf16)s;
    }
    __syncthreads();  // B1: PMA + rt visible

    // per-edge-type: fc1 (MFMA, bias folded) -> mf2 GEMM -> relu*rt accum in ALM
#pragma unroll 1
    for (int ty = 0; ty < 2; ++ty) {
      {
        // fc1: A = PMA [64][32], B = mf1 frags from global (1 x 16B/lane per wave)
        const char* src = wfb + 524288 + ty * 16384 + ((size_t)(wv * 64 + lane)) * 16;
        bf16x8 wb = *(const bf16x8*)(src);
        f32x4 fa[4];
#pragma unroll
        for (int mt = 0; mt < 4; ++mt) fa[mt] = (f32x4){0.f, 0.f, 0.f, 0.f};
#pragma unroll
        for (int mt = 0; mt < 4; ++mt) {
          bf16x8 af = *(const bf16x8*)(smem + LDS_PMA + (mt * 16 + col16) * 64 + lg * 16);
          fa[mt] = MFMA16(af, wb, fa[mt]);
        }
        // relu -> ACT (swizzled act layout), this wave's 16 cols
        const int cb = (wv * 16 + col16) * 2;
#pragma unroll
        for (int mt = 0; mt < 4; ++mt)
#pragma unroll
          for (int r = 0; r < 4; ++r) {
            int e = mt * 16 + lg * 4 + r;
            *(__bf16*)(smem + LDS_ACT + aoff(e, cb)) = (__bf16)fmaxf(fa[mt][r], 0.f);
          }
      }
      // mf2[ty]: ACT @ W (chunk0 sync inside covers ACT writes)
      f32x4 acc[4];
#pragma unroll
      for (int mt = 0; mt < 4; ++mt) acc[mt] = (f32x4){0.f, 0.f, 0.f, 0.f};
      gemm256d(smem, wfb + (size_t)ty * 131072, LDS_ACT, lane, wv, acc);
      const float bbv = bs[ty * 256 + wv * 16 + col16];
      const int cb = (wv * 16 + col16) * 2;
#pragma unroll
      for (int mt = 0; mt < 4; ++mt) {
#pragma unroll
        for (int r = 0; r < 4; ++r) {
          int e = mt * 16 + lg * 4 + r;
          float v = fmaxf(acc[mt][r] + bbv, 0.f) * rt[e * 2 + ty];
          __bf16* p = (__bf16*)(smem + LDS_ALM + aoff(e, cb));
          if (ty == 1) v += (float)*p;  // own patch: same thread wrote it at ty=0
          *p = (__bf16)v;
        }
      }
      __syncthreads();  // B3/B5: ALM visible / ACT free for next fc1
    }

    // at1_l1: ALM @ W -> elu -> ACT
    {
      f32x4 acc[4];
#pragma unroll
      for (int mt = 0; mt < 4; ++mt) acc[mt] = (f32x4){0.f, 0.f, 0.f, 0.f};
      gemm256d(smem, wfb + (size_t)2 * 131072, LDS_ALM, lane, wv, acc);
      const float bbv = bs[512 + wv * 16 + col16];
      const int cb = (wv * 16 + col16) * 2;
#pragma unroll
      for (int mt = 0; mt < 4; ++mt)
#pragma unroll
        for (int r = 0; r < 4; ++r) {
          int e = mt * 16 + lg * 4 + r;
          *(__bf16*)(smem + LDS_ACT + aoff(e, cb)) = (__bf16)eluf(acc[mt][r] + bbv);
        }
    }
    __syncthreads();  // B6: ACT(elu) visible; ALM reads done before B-frag overwrite

    // at1_l2: ACT @ W -> elu*sc+be -> h_edges B-frags in ALM
    {
      f32x4 acc[4];
#pragma unroll
      for (int mt = 0; mt < 4; ++mt) acc[mt] = (f32x4){0.f, 0.f, 0.f, 0.f};
      gemm256d(smem, wfb + (size_t)3 * 131072, LDS_ACT, lane, wv, acc);
      const int col = wv * 16 + col16;
      const float b_ = bs[768 + col], s1 = bs[1024 + col], s2 = bs[1280 + col];
      const int j0 = (lg & 1) * 4;
#pragma unroll
      for (int mt = 0; mt < 4; ++mt) {
        const int khalf = mt >> 1;
        const int lane2 = col16 | ((((mt & 1) * 2) + (lg >> 1)) << 4);
        bf16x4 pk;
#pragma unroll
        for (int r = 0; r < 4; ++r)
          pk[r] = (__bf16)(eluf(acc[mt][r] + b_) * s1 + s2);
        int addr = (((khalf * 16 + wv) * 64 + lane2) * 8 + j0) * 2;
        *(bf16x4*)(smem + LDS_ALM + addr) = pk;
      }
    }
    __syncthreads();  // B7: B-frags visible

    // agg GEMM: ag += rel_rec[tile]^T @ h_edges  (M=48, N=256, K=64)
    const bf16x8* rraw = (const bf16x8*)rra + (size_t)tile * 384;
#pragma unroll
    for (int kt2 = 0; kt2 < 2; ++kt2) {
      bf16x8 b = *(const bf16x8*)(smem + LDS_ALM + ((kt2 * 16 + wv) * 64 + lane) * 16);
#pragma unroll
      for (int mt2 = 0; mt2 < 3; ++mt2) {
        bf16x8 a = rraw[(kt2 * 3 + mt2) * 64 + lane];
        ag[mt2] = MFMA16(a, b, ag[mt2]);
      }
    }
    // next tile's first ALM/ACT writes are gated by later barriers
  }

  if (MODE == 1) {
    __bf16* dst = partb + (size_t)blockIdx.x * Nn * Hh;
    const int h = wv * 16 + col16;
#pragma unroll
    for (int mt2 = 0; mt2 < 3; ++mt2)
#pragma unroll
      for (int r = 0; r < 4; ++r) {
        int n = mt2 * 16 + lg * 4 + r;
        dst[n * Hh + h] = (__bf16)ag[mt2][r];
      }
  } else {
    float* dst = g_agg + (size_t)slice * Nn * Hh;
    const int h = wv * 16 + col16;
#pragma unroll
    for (int mt2 = 0; mt2 < 3; ++mt2)
#pragma unroll
      for (int r = 0; r < 4; ++r) {
        int n = mt2 * 16 + lg * 4 + r;
        atomicAdd(dst + n * Hh + h, ag[mt2][r]);
      }
  }
}

// 4 weight matrices [256][256] fp32 -> bf16 MFMA B-fragment-linear
__global__ void prep_frag(const float* __restrict__ mf2_w, const float* __restrict__ at1_w1,
                          const float* __restrict__ at1_w2, __bf16* __restrict__ wfdst) {
  int id = blockIdx.x * 256 + threadIdx.x;  // 32768 total
  int mat = id >> 13, r = id & 8191;
  int kt = r >> 10, q = r & 1023, nt = q >> 6, l = q & 63;
  int row = nt * 16 + (l & 15), col = kt * 32 + (l >> 4) * 8;
  const float* src = (mat == 0) ? mf2_w : (mat == 1) ? (mf2_w + 65536)
                   : (mat == 2) ? at1_w1 : at1_w2;
  const float* p = src + row * 256 + col;
  __bf16* d = wfdst + (size_t)mat * 65536 + ((size_t)(kt * 16 + nt) * 64 + l) * 8;
#pragma unroll
  for (int j = 0; j < 8; ++j) d[j] = (__bf16)p[j];
}

// mf1 (2F=8 -> H=256) as K=32-padded B-frags; bias folded at k=8
__global__ void prep_mf1(const float* __restrict__ mf1_w, const float* __restrict__ mf1_b,
                         __bf16* __restrict__ wfdst) {
  int id = blockIdx.x * 256 + threadIdx.x;  // 2048 total
  int ty = id >> 10, q = id & 1023, ntg = q >> 6, l = q & 63;
  int col = ntg * 16 + (l & 15);
  int k0 = (l >> 4) * 8;
  bf16x8 v;
#pragma unroll
  for (int j = 0; j < 8; ++j) {
    int k = k0 + j;
    float x = (k < 8) ? mf1_w[ty * 2048 + col * 8 + k]
            : (k == 8) ? mf1_b[ty * 256 + col] : 0.f;
    v[j] = (__bf16)x;
  }
  ((bf16x8*)(wfdst + 262144))[id] = v;
}

// rel_rec^T per-tile bf16 A-fragments: rra[tile][kt2(2)][mt2(3)][lane][8]
__global__ void prep_rra(const float* __restrict__ rel_rec, __bf16* __restrict__ rra) {
  int id = blockIdx.x * 256 + threadIdx.x;  // 36*384 = 13824
  if (id >= 13824) return;
  int tile = id / 384, r = id % 384;
  int kt2 = r / 192, r2 = r % 192, mt2 = r2 >> 6, l = r2 & 63;
  int ebase = tile * 64 + kt2 * 32 + (l >> 4) * 8;
  int n = mt2 * 16 + (l & 15);
  bf16x8 v;
#pragma unroll
  for (int j = 0; j < 8; ++j) {
    int e = ebase + j;
    v[j] = (__bf16)((e < Ee) ? rel_rec[(size_t)e * Nn + n] : 0.f);
  }
  ((bf16x8*)rra)[id] = v;
}

// transpose node-side weights (fp32) for coalesced lane reads
__global__ void prep_node(const float* __restrict__ at5_w1, const float* __restrict__ at5_w2,
                          const float* __restrict__ o1_w, const float* __restrict__ o2_w,
                          const float* __restrict__ o3_w, float* __restrict__ ws) {
  int id = blockIdx.x * 256 + threadIdx.x;
  float* T1 = ws;
  float* T2 = T1 + 67600;
  float* To1 = T2 + 67600;
  float* To2 = To1 + 66560;
  float* To3 = To2 + 65536;
  if (id < 67600) { int o = id % 260, k = id / 260; T1[k * 260 + o] = at5_w1[o * 260 + k]; return; }
  id -= 67600;
  if (id < 67600) { int o = id % 260, k = id / 260; T2[k * 260 + o] = at5_w2[o * 260 + k]; return; }
  id -= 67600;
  if (id < 66560) { int o = id & 255, k = id >> 8; To1[k * 256 + o] = o1_w[o * 260 + k]; return; }
  id -= 66560;
  if (id < 65536) { int o = id & 255, k = id >> 8; To2[k * 256 + o] = o2_w[o * 256 + k]; return; }
  id -= 65536;
  if (id < 1024) { int f = id & 3, k = id >> 2; To3[k * 4 + f] = o3_w[f * 256 + k]; }
}

// 512 blocks x 6 node-rows each
template<int MODE>
__global__ __launch_bounds__(256, 4)
void node_kernel(const float* __restrict__ g_agg, const __bf16* __restrict__ partb,
                 const float* __restrict__ x,
                 const float* __restrict__ T1, const float* __restrict__ T2,
                 const float* __restrict__ To1, const float* __restrict__ To2,
                 const float* __restrict__ To3, const float* __restrict__ at5_b1,
                 const float* __restrict__ at5_b2, const float* __restrict__ at5_g,
                 const float* __restrict__ at5_be, const float* __restrict__ o1_b,
                 const float* __restrict__ o2_b, const float* __restrict__ o3_b,
                 float* __restrict__ out) {
  __shared__ float bufA[6 * 264], bufB[6 * 264], xres[6 * 4];
  const int tid = threadIdx.x;
  const int slice = blockIdx.x >> 3, rg = blockIdx.x & 7;
  const int n0 = rg * 6;
  for (int t = tid; t < 6 * 256; t += 256) {
    int r = t >> 8, h = t & 255;
    float s;
    if (MODE == 1) {
      s = 0.f;
#pragma unroll
      for (int sp = 0; sp < 4; ++sp)
        s += (float)partb[((((size_t)slice * 4 + sp) * Nn) + n0 + r) * Hh + h];
    } else {
      s = g_agg[(size_t)slice * 12288 + (size_t)(n0 + r) * 256 + h];
    }
    bufA[r * 264 + h] = s;
  }
  if (tid < 24) {
    int r = tid >> 2, f = tid & 3;
    float v = x[(size_t)slice * 192 + (n0 + r) * 4 + f];
    bufA[r * 264 + 256 + f] = v;
    xres[tid] = v;
  }
  __syncthreads();

  auto layer = [&](const float* WT, const float* bsrc, const float* in, float* outb,
                   int K, int O, int act, const float* gsc, const float* gbe) {
    for (int o = tid; o < O; o += 256) {
      float a[6];
      float bb = bsrc[o];
#pragma unroll
      for (int r = 0; r < 6; ++r) a[r] = bb;
      for (int k = 0; k < K; ++k) {
        float w = WT[k * O + o];
#pragma unroll
        for (int r = 0; r < 6; ++r) a[r] = fmaf(in[r * 264 + k], w, a[r]);
      }
      float scv = 1.f, bev = 0.f;
      if (act == 2) { scv = gsc[o] * BN_RS; bev = gbe[o]; }
#pragma unroll
      for (int r = 0; r < 6; ++r) {
        float v = a[r];
        v = (act == 0) ? fmaxf(v, 0.f) : eluf(v);
        if (act == 2) v = v * scv + bev;
        outb[r * 264 + o] = v;
      }
    }
    __syncthreads();
  };

  layer(T1, at5_b1, bufA, bufB, 260, 260, 1, nullptr, nullptr);
  layer(T2, at5_b2, bufB, bufA, 260, 260, 2, at5_g, at5_be);
  layer(To1, o1_b, bufA, bufB, 260, 256, 0, nullptr, nullptr);
  layer(To2, o2_b, bufB, bufA, 256, 256, 0, nullptr, nullptr);
  if (tid < 24) {
    int r = tid >> 2, f = tid & 3;
    float s = o3_b[f];
    for (int k = 0; k < 256; ++k) s = fmaf(bufA[r * 264 + k], To3[k * 4 + f], s);
    out[(size_t)slice * 192 + (n0 + r) * 4 + f] = xres[tid] + s;
  }
}

extern "C" void kernel_launch(void* const* d_in, const int* in_sizes, int n_in,
                              void* d_out, int out_size, void* d_ws, size_t ws_size,
                              hipStream_t stream) {
  const float* x = (const float*)d_in[0];
  const float* rel_rec = (const float*)d_in[1];
  const float* rel_send = (const float*)d_in[2];
  const float* rel_type = (const float*)d_in[3];
  const float* mf1_w = (const float*)d_in[4];
  const float* mf1_b = (const float*)d_in[5];
  const float* mf2_w = (const float*)d_in[6];
  const float* mf2_b = (const float*)d_in[7];
  const float* at1_w1 = (const float*)d_in[8];
  const float* at1_b1 = (const float*)d_in[9];
  const float* at1_w2 = (const float*)d_in[10];
  const float* at1_b2 = (const float*)d_in[11];
  const float* at1_g = (const float*)d_in[12];
  const float* at1_be = (const float*)d_in[13];
  const float* at5_w1 = (const float*)d_in[14];
  const float* at5_b1 = (const float*)d_in[15];
  const float* at5_w2 = (const float*)d_in[16];
  const float* at5_b2 = (const float*)d_in[17];
  const float* at5_g = (const float*)d_in[18];
  const float* at5_be = (const float*)d_in[19];
  const float* o1_w = (const float*)d_in[20];
  const float* o1_b = (const float*)d_in[21];
  const float* o2_w = (const float*)d_in[22];
  const float* o2_b = (const float*)d_in[23];
  const float* o3_w = (const float*)d_in[24];
  const float* o3_b = (const float*)d_in[25];

  char* ws = (char*)d_ws;
  __bf16* wf = (__bf16*)(ws + WS_WF);
  __bf16* rra = (__bf16*)(ws + WS_RRA);
  float* tnode = (float*)(ws + WS_TN);
  float* g_agg = (float*)(ws + WS_AGG);
  __bf16* partb = (__bf16*)(ws + WS_PB);

  const int mode = (ws_size >= WS_NEED1) ? 1 : 0;

  prep_frag<<<128, 256, 0, stream>>>(mf2_w, at1_w1, at1_w2, wf);
  prep_mf1<<<8, 256, 0, stream>>>(mf1_w, mf1_b, wf);
  prep_rra<<<54, 256, 0, stream>>>(rel_rec, rra);
  prep_node<<<1049, 256, 0, stream>>>(at5_w1, at5_w2, o1_w, o2_w, o3_w, tnode);

  if (mode == 1) {
    hipFuncSetAttribute((const void*)edge_kernel<1>,
                        hipFuncAttributeMaxDynamicSharedMemorySize, LDS_EDGE_BYTES);
    edge_kernel<1><<<BT * 4, 1024, LDS_EDGE_BYTES, stream>>>(
        x, rel_rec, rel_send, rel_type, mf2_b, at1_b1, at1_b2,
        at1_g, at1_be, wf, rra, g_agg, partb);
    node_kernel<1><<<512, 256, 0, stream>>>(g_agg, partb, x, tnode, tnode + 67600,
                                            tnode + 135200, tnode + 201760, tnode + 267296,
                                            at5_b1, at5_b2, at5_g, at5_be,
                                            o1_b, o2_b, o3_b, (float*)d_out);
  } else {
    hipMemsetAsync(g_agg, 0, (size_t)BT * Nn * Hh * 4, stream);
    hipFuncSetAttribute((const void*)edge_kernel<0>,
                        hipFuncAttributeMaxDynamicSharedMemorySize, LDS_EDGE_BYTES);
    edge_kernel<0><<<BT * 4, 1024, LDS_EDGE_BYTES, stream>>>(
        x, rel_rec, rel_send, rel_type, mf2_b, at1_b1, at1_b2,
        at1_g, at1_be, wf, rra, g_agg, partb);
    node_kernel<0><<<512, 256, 0, stream>>>(g_agg, partb, x, tnode, tnode + 67600,
                                            tnode + 135200, tnode + 201760, tnode + 267296,
                                            at5_b1, at5_b2, at5_g, at5_be,
                                            o1_b, o2_b, o3_b, (float*)d_out);
  }
}

// Round 13
// 291.098 us; speedup vs baseline: 1.5743x; 1.0928x over previous
//
#include <hip/hip_runtime.h>
#include <hip/hip_bf16.h>
#include <math.h>

typedef __bf16 bf16x8 __attribute__((ext_vector_type(8)));
typedef __bf16 bf16x4 __attribute__((ext_vector_type(4)));
typedef float f32x4 __attribute__((ext_vector_type(4)));

#define MFMA16(a,b,c) __builtin_amdgcn_mfma_f32_16x16x32_bf16(a,b,c,0,0,0)

static constexpr int Nn = 48, Hh = 256;
static constexpr int Ee = 2256, BT = 64;
static constexpr int ETILE = 64, NTILES = 36;          // 36*64 = 2304 >= 2256
static constexpr float BN_RS = 0.9999950000374998f;    // 1/sqrt(1+1e-5)

// ---- ws layout (bytes) ----
static constexpr size_t WS_WF  = 0;         // 4 mats frag-linear + mf1 frags: 557056
static constexpr size_t WS_RRA = 557056;    // 36*2*3*64*8 bf16 = 221184
static constexpr size_t WS_TN  = 778240;    // 268320 f32 = 1073280
static constexpr size_t WS_AGG = 1851520;   // g_agg [64][48][256] f32 = 3145728 (MODE0)
static constexpr size_t WS_PB  = 4997248;   // bf16 partials [256][48][256] = 6291456 (MODE1)
static constexpr size_t WS_NEED1 = WS_PB + 6291456;  // 11288704

// ---- LDS layout (bytes), total 142592; 1024 threads, 1 block/CU ----
static constexpr int LDS_ACT = 0;        // [64][512B] swizzled act
static constexpr int LDS_ALM = 32768;    // [64][512B] all_msgs act, then h_edges B-frags
static constexpr int LDS_WSG = 65536;    // 2 x 32KB ring of weight chunks (wave-private rows)
static constexpr int LDS_PMA = 131072;   // [64][64B] pre_msg bf16, K=32 padded (k=8 const 1.0)
static constexpr int LDS_RT  = 135168;   // [64][2] f32
static constexpr int LDS_BS  = 135680;   // 1536 f32 biases
static constexpr int LDS_XS  = 141824;   // 192 f32
static constexpr int LDS_EDGE_BYTES = 142592;

__device__ __forceinline__ float eluf(float v) { return v > 0.f ? v : __expf(v) - 1.f; }

typedef __attribute__((address_space(1))) const unsigned int as1_uint;
typedef __attribute__((address_space(3))) unsigned int as3_uint;
__device__ __forceinline__ void gload16(const void* g, void* l) {
  __builtin_amdgcn_global_load_lds((as1_uint*)g, (as3_uint*)l, 16, 0, 0);
}

__device__ __forceinline__ int aoff(int e, int colbyte) {
  return e * 512 + (colbyte ^ ((e & 7) << 4));
}

// lgkm-only barrier: LDS writes visible, DMA (vmcnt) stays in flight (T4).
#define LBAR() do { asm volatile("s_waitcnt lgkmcnt(0)" ::: "memory"); \
  __builtin_amdgcn_s_barrier(); __builtin_amdgcn_sched_barrier(0); } while (0)
// per-wave counted DMA wait: oldest chunk (2 loads) landed, 2 newer stay in flight.
#define VWAIT2() do { asm volatile("s_waitcnt vmcnt(2)" ::: "memory"); \
  __builtin_amdgcn_sched_barrier(0); } while (0)

// wave wv stages ONLY its own B rows {wv, wv+16} of a 32KB chunk (2KB via 2 DMA).
__device__ __forceinline__ void issueW(const char* chunkSrc, char* wsgbuf, int wv, int lane) {
  gload16(chunkSrc + wv * 1024 + lane * 16, wsgbuf + wv * 1024);
  gload16(chunkSrc + (16 + wv) * 1024 + lane * 16, wsgbuf + (16 + wv) * 1024);
}

// K=256 GEMM, 16-wave split, wave-private software-pipelined weight DMA.
// Invariant on entry: this wave's chunks 0,1 of wmat already issued (in order),
// and they are this wave's 2 oldest outstanding vmem ops. Iterations 2,3
// pre-issue nextw's chunks 0,1, re-establishing the invariant. NO barriers.
__device__ __forceinline__ void gemmK(char* smem, const char* wmat, const char* nextw,
                                      int abase, int lane, int wv, f32x4 acc[4]) {
  char* wsg = smem + LDS_WSG;
  const int kgb = (lane >> 4) * 16;
  const int c16 = lane & 15;
#pragma unroll
  for (int c = 0; c < 4; ++c) {
    VWAIT2();  // chunk c landed (this wave's rows)
#pragma unroll
    for (int ks = 0; ks < 2; ++ks) {
      const int kt = c * 2 + ks;
      bf16x8 bfr = *(const bf16x8*)(wsg + (c & 1) * 32768 + ((ks * 16 + wv) * 64 + lane) * 16);
#pragma unroll
      for (int mt = 0; mt < 4; ++mt) {
        int r = mt * 16 + c16;
        bf16x8 af = *(const bf16x8*)(smem + abase + r * 512 + ((kt * 64 + kgb) ^ ((r & 7) << 4)));
        acc[mt] = MFMA16(af, bfr, acc[mt]);
      }
    }
    __builtin_amdgcn_sched_barrier(0);  // keep re-issue below the ds_reads above
    const char* src = (c < 2) ? (wmat + (c + 2) * 32768) : (nextw + (c - 2) * 32768);
    issueW(src, wsg + (c & 1) * 32768, wv, lane);
  }
}

template<int MODE>
__global__ __launch_bounds__(1024)
void edge_kernel(const float* __restrict__ x, const float* __restrict__ rel_rec,
                 const float* __restrict__ rel_send, const float* __restrict__ rel_type,
                 const float* __restrict__ mf2_b, const float* __restrict__ at1_b1,
                 const float* __restrict__ at1_b2, const float* __restrict__ at1_g,
                 const float* __restrict__ at1_be, const __bf16* __restrict__ wf,
                 const __bf16* __restrict__ rra, float* __restrict__ g_agg,
                 __bf16* __restrict__ partb) {
  extern __shared__ char smem[];
  float* xs = (float*)(smem + LDS_XS);
  float* rt = (float*)(smem + LDS_RT);
  float* bs = (float*)(smem + LDS_BS);
  const char* wfb = (const char*)wf;

  const int tid = threadIdx.x;
  const int lane = tid & 63;
  const int wv = tid >> 6;                // 0..15
  const int lg = lane >> 4;
  const int col16 = lane & 15;
  const int slice = blockIdx.x >> 2;
  const int split = blockIdx.x & 3;
  const int t_begin = split * 9;

  // start the cross-GEMM DMA pipeline: mf2_0 chunks 0,1 (this wave's rows)
  issueW(wfb, smem + LDS_WSG, wv, lane);
  issueW(wfb + 32768, smem + LDS_WSG + 32768, wv, lane);

  // block-start preloads: xs, bias table, PMA zero+ones
  if (tid < Nn * 4) xs[tid] = x[slice * Nn * 4 + tid];
#pragma unroll
  for (int i = 0; i < 2; ++i) {
    int t = i * 1024 + tid;
    if (t < 1536) {
      int which = t >> 8, o = t & 255;
      float v;
      switch (which) {
        case 0: v = mf2_b[o]; break;
        case 1: v = mf2_b[256 + o]; break;
        case 2: v = at1_b1[o]; break;
        case 3: v = at1_b2[o]; break;
        case 4: v = at1_g[o] * BN_RS; break;
        default: v = at1_be[o]; break;
      }
      bs[t] = v;
    }
  }
  ((unsigned int*)(smem + LDS_PMA))[tid] = ((tid & 15) == 4) ? 0x00003f80u : 0u;

  f32x4 ag[3];
#pragma unroll
  for (int a = 0; a < 3; ++a) ag[a] = (f32x4){0.f, 0.f, 0.f, 0.f};
  LBAR();

  for (int tt = 0; tt < 9; ++tt) {
    const int tile = t_begin + tt;
    const int e0 = tile * ETILE;
    const int ne = (Ee - e0 < ETILE) ? (Ee - e0) : ETILE;

    if (tid < ETILE * 2) {
      int e = tid >> 1, i2 = tid & 1;
      rt[tid] = (e < ne) ? rel_type[((size_t)slice * Ee + e0 + e) * 2 + i2] : 0.f;
    }
    if (tid < 512) {
      int c = tid >> 6, e = tid & 63;
      float s = 0.f;
      if (e < ne) {
        const float* rel = ((c < 4) ? rel_send : rel_rec) + (size_t)(e0 + e) * Nn;
        int f = c & 3;
#pragma unroll
        for (int n = 0; n < Nn; ++n) s += rel[n] * xs[n * 4 + f];
      }
      *(__bf16*)(smem + LDS_PMA + e * 64 + c * 2) = (__bf16)s;
    }
    LBAR();  // B1: PMA + rt visible

#pragma unroll 1
    for (int ty = 0; ty < 2; ++ty) {
      {
        // fc1: A = PMA [64][32] (bias folded at k=8), B = mf1 frags from global
        const char* src = wfb + 524288 + ty * 16384 + ((size_t)(wv * 64 + lane)) * 16;
        bf16x8 wb = *(const bf16x8*)(src);
        f32x4 fa[4];
#pragma unroll
        for (int mt = 0; mt < 4; ++mt) fa[mt] = (f32x4){0.f, 0.f, 0.f, 0.f};
#pragma unroll
        for (int mt = 0; mt < 4; ++mt) {
          bf16x8 af = *(const bf16x8*)(smem + LDS_PMA + (mt * 16 + col16) * 64 + lg * 16);
          fa[mt] = MFMA16(af, wb, fa[mt]);
        }
        const int cb = (wv * 16 + col16) * 2;
#pragma unroll
        for (int mt = 0; mt < 4; ++mt)
#pragma unroll
          for (int r = 0; r < 4; ++r) {
            int e = mt * 16 + lg * 4 + r;
            *(__bf16*)(smem + LDS_ACT + aoff(e, cb)) = (__bf16)fmaxf(fa[mt][r], 0.f);
          }
      }
      LBAR();  // ACT visible to all waves

      f32x4 acc[4];
#pragma unroll
      for (int mt = 0; mt < 4; ++mt) acc[mt] = (f32x4){0.f, 0.f, 0.f, 0.f};
      const char* wm = wfb + (size_t)ty * 131072;
      const char* nx = wfb + (size_t)(ty + 1) * 131072;  // mf2_1 then at1_w1
      gemmK(smem, wm, nx, LDS_ACT, lane, wv, acc);
      const float bbv = bs[ty * 256 + wv * 16 + col16];
      const int cb = (wv * 16 + col16) * 2;
#pragma unroll
      for (int mt = 0; mt < 4; ++mt) {
#pragma unroll
        for (int r = 0; r < 4; ++r) {
          int e = mt * 16 + lg * 4 + r;
          float v = fmaxf(acc[mt][r] + bbv, 0.f) * rt[e * 2 + ty];
          __bf16* p = (__bf16*)(smem + LDS_ALM + aoff(e, cb));
          if (ty == 1) v += (float)*p;  // own patch: same thread wrote it at ty=0
          *p = (__bf16)v;
        }
      }
      LBAR();  // epilogue done: ACT free for next fc1 / ALM visible for at1_l1
    }

    // at1_l1: ALM @ W -> elu -> ACT
    {
      f32x4 acc[4];
#pragma unroll
      for (int mt = 0; mt < 4; ++mt) acc[mt] = (f32x4){0.f, 0.f, 0.f, 0.f};
      gemmK(smem, wfb + (size_t)2 * 131072, wfb + (size_t)3 * 131072, LDS_ALM, lane, wv, acc);
      const float bbv = bs[512 + wv * 16 + col16];
      const int cb = (wv * 16 + col16) * 2;
#pragma unroll
      for (int mt = 0; mt < 4; ++mt)
#pragma unroll
        for (int r = 0; r < 4; ++r) {
          int e = mt * 16 + lg * 4 + r;
          *(__bf16*)(smem + LDS_ACT + aoff(e, cb)) = (__bf16)eluf(acc[mt][r] + bbv);
        }
    }
    LBAR();  // ACT(elu) visible; all waves out of l1-gemm

    // at1_l2: ACT @ W -> elu*sc+be -> h_edges B-frags in ALM
    {
      f32x4 acc[4];
#pragma unroll
      for (int mt = 0; mt < 4; ++mt) acc[mt] = (f32x4){0.f, 0.f, 0.f, 0.f};
      gemmK(smem, wfb + (size_t)3 * 131072, wfb, LDS_ACT, lane, wv, acc);  // next: mf2_0 (next tile)
      const int col = wv * 16 + col16;
      const float b_ = bs[768 + col], s1 = bs[1024 + col], s2 = bs[1280 + col];
      const int j0 = (lg & 1) * 4;
#pragma unroll
      for (int mt = 0; mt < 4; ++mt) {
        const int khalf = mt >> 1;
        const int lane2 = col16 | ((((mt & 1) * 2) + (lg >> 1)) << 4);
        bf16x4 pk;
#pragma unroll
        for (int r = 0; r < 4; ++r)
          pk[r] = (__bf16)(eluf(acc[mt][r] + b_) * s1 + s2);
        int addr = (((khalf * 16 + wv) * 64 + lane2) * 8 + j0) * 2;
        *(bf16x4*)(smem + LDS_ALM + addr) = pk;
      }
    }
    LBAR();  // B7: B-frags visible; all waves out of l2-gemm

    // agg GEMM: ag += rel_rec[tile]^T @ h_edges  (M=48, N=256, K=64)
    const bf16x8* rraw = (const bf16x8*)rra + (size_t)tile * 384;
#pragma unroll
    for (int kt2 = 0; kt2 < 2; ++kt2) {
      bf16x8 b = *(const bf16x8*)(smem + LDS_ALM + ((kt2 * 16 + wv) * 64 + lane) * 16);
#pragma unroll
      for (int mt2 = 0; mt2 < 3; ++mt2) {
        bf16x8 a = rraw[(kt2 * 3 + mt2) * 64 + lane];
        ag[mt2] = MFMA16(a, b, ag[mt2]);
      }
    }
    // next tile's PMA/rt writes are disjoint from agg's reads; B1 gates fc1
  }

  if (MODE == 1) {
    __bf16* dst = partb + (size_t)blockIdx.x * Nn * Hh;
    const int h = wv * 16 + col16;
#pragma unroll
    for (int mt2 = 0; mt2 < 3; ++mt2)
#pragma unroll
      for (int r = 0; r < 4; ++r) {
        int n = mt2 * 16 + lg * 4 + r;
        dst[n * Hh + h] = (__bf16)ag[mt2][r];
      }
  } else {
    float* dst = g_agg + (size_t)slice * Nn * Hh;
    const int h = wv * 16 + col16;
#pragma unroll
    for (int mt2 = 0; mt2 < 3; ++mt2)
#pragma unroll
      for (int r = 0; r < 4; ++r) {
        int n = mt2 * 16 + lg * 4 + r;
        atomicAdd(dst + n * Hh + h, ag[mt2][r]);
      }
  }
}

// merged prep: blocks [0,128) frag, [128,136) mf1, [136,190) rra, [190,1239) node
__global__ void prep_all(const float* __restrict__ mf2_w, const float* __restrict__ at1_w1,
                         const float* __restrict__ at1_w2, const float* __restrict__ mf1_w,
                         const float* __restrict__ mf1_b, const float* __restrict__ rel_rec,
                         const float* __restrict__ at5_w1, const float* __restrict__ at5_w2,
                         const float* __restrict__ o1_w, const float* __restrict__ o2_w,
                         const float* __restrict__ o3_w,
                         __bf16* __restrict__ wfdst, __bf16* __restrict__ rra,
                         float* __restrict__ tn) {
  int b = blockIdx.x;
  if (b < 128) {
    int id = b * 256 + threadIdx.x;  // 32768
    int mat = id >> 13, r = id & 8191;
    int kt = r >> 10, q = r & 1023, nt = q >> 6, l = q & 63;
    int row = nt * 16 + (l & 15), col = kt * 32 + (l >> 4) * 8;
    const float* src = (mat == 0) ? mf2_w : (mat == 1) ? (mf2_w + 65536)
                     : (mat == 2) ? at1_w1 : at1_w2;
    const float* p = src + row * 256 + col;
    __bf16* d = wfdst + (size_t)mat * 65536 + ((size_t)(kt * 16 + nt) * 64 + l) * 8;
#pragma unroll
    for (int j = 0; j < 8; ++j) d[j] = (__bf16)p[j];
    return;
  }
  if (b < 136) {
    int id = (b - 128) * 256 + threadIdx.x;  // 2048
    int ty = id >> 10, q = id & 1023, ntg = q >> 6, l = q & 63;
    int col = ntg * 16 + (l & 15);
    int k0 = (l >> 4) * 8;
    bf16x8 v;
#pragma unroll
    for (int j = 0; j < 8; ++j) {
      int k = k0 + j;
      float xv = (k < 8) ? mf1_w[ty * 2048 + col * 8 + k]
               : (k == 8) ? mf1_b[ty * 256 + col] : 0.f;
      v[j] = (__bf16)xv;
    }
    ((bf16x8*)(wfdst + 262144))[id] = v;
    return;
  }
  if (b < 190) {
    int id = (b - 136) * 256 + threadIdx.x;  // 13824
    if (id >= 13824) return;
    int tile = id / 384, r = id % 384;
    int kt2 = r / 192, r2 = r % 192, mt2 = r2 >> 6, l = r2 & 63;
    int ebase = tile * 64 + kt2 * 32 + (l >> 4) * 8;
    int n = mt2 * 16 + (l & 15);
    bf16x8 v;
#pragma unroll
    for (int j = 0; j < 8; ++j) {
      int e = ebase + j;
      v[j] = (__bf16)((e < Ee) ? rel_rec[(size_t)e * Nn + n] : 0.f);
    }
    ((bf16x8*)rra)[id] = v;
    return;
  }
  int id = (b - 190) * 256 + threadIdx.x;
  float* T1 = tn;
  float* T2 = T1 + 67600;
  float* To1 = T2 + 67600;
  float* To2 = To1 + 66560;
  float* To3 = To2 + 65536;
  if (id < 67600) { int o = id % 260, k = id / 260; T1[k * 260 + o] = at5_w1[o * 260 + k]; return; }
  id -= 67600;
  if (id < 67600) { int o = id % 260, k = id / 260; T2[k * 260 + o] = at5_w2[o * 260 + k]; return; }
  id -= 67600;
  if (id < 66560) { int o = id & 255, k = id >> 8; To1[k * 256 + o] = o1_w[o * 260 + k]; return; }
  id -= 66560;
  if (id < 65536) { int o = id & 255, k = id >> 8; To2[k * 256 + o] = o2_w[o * 256 + k]; return; }
  id -= 65536;
  if (id < 1024) { int f = id & 3, k = id >> 2; To3[k * 4 + f] = o3_w[f * 256 + k]; }
}

// 512 blocks x 6 node-rows each
template<int MODE>
__global__ __launch_bounds__(256, 4)
void node_kernel(const float* __restrict__ g_agg, const __bf16* __restrict__ partb,
                 const float* __restrict__ x,
                 const float* __restrict__ T1, const float* __restrict__ T2,
                 const float* __restrict__ To1, const float* __restrict__ To2,
                 const float* __restrict__ To3, const float* __restrict__ at5_b1,
                 const float* __restrict__ at5_b2, const float* __restrict__ at5_g,
                 const float* __restrict__ at5_be, const float* __restrict__ o1_b,
                 const float* __restrict__ o2_b, const float* __restrict__ o3_b,
                 float* __restrict__ out) {
  __shared__ float bufA[6 * 264], bufB[6 * 264], xres[6 * 4];
  const int tid = threadIdx.x;
  const int slice = blockIdx.x >> 3, rg = blockIdx.x & 7;
  const int n0 = rg * 6;
  for (int t = tid; t < 6 * 256; t += 256) {
    int r = t >> 8, h = t & 255;
    float s;
    if (MODE == 1) {
      s = 0.f;
#pragma unroll
      for (int sp = 0; sp < 4; ++sp)
        s += (float)partb[((((size_t)slice * 4 + sp) * Nn) + n0 + r) * Hh + h];
    } else {
      s = g_agg[(size_t)slice * 12288 + (size_t)(n0 + r) * 256 + h];
    }
    bufA[r * 264 + h] = s;
  }
  if (tid < 24) {
    int r = tid >> 2, f = tid & 3;
    float v = x[(size_t)slice * 192 + (n0 + r) * 4 + f];
    bufA[r * 264 + 256 + f] = v;
    xres[tid] = v;
  }
  __syncthreads();

  auto layer = [&](const float* WT, const float* bsrc, const float* in, float* outb,
                   int K, int O, int act, const float* gsc, const float* gbe) {
    for (int o = tid; o < O; o += 256) {
      float a[6];
      float bb = bsrc[o];
#pragma unroll
      for (int r = 0; r < 6; ++r) a[r] = bb;
      for (int k = 0; k < K; ++k) {
        float w = WT[k * O + o];
#pragma unroll
        for (int r = 0; r < 6; ++r) a[r] = fmaf(in[r * 264 + k], w, a[r]);
      }
      float scv = 1.f, bev = 0.f;
      if (act == 2) { scv = gsc[o] * BN_RS; bev = gbe[o]; }
#pragma unroll
      for (int r = 0; r < 6; ++r) {
        float v = a[r];
        v = (act == 0) ? fmaxf(v, 0.f) : eluf(v);
        if (act == 2) v = v * scv + bev;
        outb[r * 264 + o] = v;
      }
    }
    __syncthreads();
  };

  layer(T1, at5_b1, bufA, bufB, 260, 260, 1, nullptr, nullptr);
  layer(T2, at5_b2, bufB, bufA, 260, 260, 2, at5_g, at5_be);
  layer(To1, o1_b, bufA, bufB, 260, 256, 0, nullptr, nullptr);
  layer(To2, o2_b, bufB, bufA, 256, 256, 0, nullptr, nullptr);
  if (tid < 24) {
    int r = tid >> 2, f = tid & 3;
    float s = o3_b[f];
    for (int k = 0; k < 256; ++k) s = fmaf(bufA[r * 264 + k], To3[k * 4 + f], s);
    out[(size_t)slice * 192 + (n0 + r) * 4 + f] = xres[tid] + s;
  }
}

extern "C" void kernel_launch(void* const* d_in, const int* in_sizes, int n_in,
                              void* d_out, int out_size, void* d_ws, size_t ws_size,
                              hipStream_t stream) {
  const float* x = (const float*)d_in[0];
  const float* rel_rec = (const float*)d_in[1];
  const float* rel_send = (const float*)d_in[2];
  const float* rel_type = (const float*)d_in[3];
  const float* mf1_w = (const float*)d_in[4];
  const float* mf1_b = (const float*)d_in[5];
  const float* mf2_w = (const float*)d_in[6];
  const float* mf2_b = (const float*)d_in[7];
  const float* at1_w1 = (const float*)d_in[8];
  const float* at1_b1 = (const float*)d_in[9];
  const float* at1_w2 = (const float*)d_in[10];
  const float* at1_b2 = (const float*)d_in[11];
  const float* at1_g = (const float*)d_in[12];
  const float* at1_be = (const float*)d_in[13];
  const float* at5_w1 = (const float*)d_in[14];
  const float* at5_b1 = (const float*)d_in[15];
  const float* at5_w2 = (const float*)d_in[16];
  const float* at5_b2 = (const float*)d_in[17];
  const float* at5_g = (const float*)d_in[18];
  const float* at5_be = (const float*)d_in[19];
  const float* o1_w = (const float*)d_in[20];
  const float* o1_b = (const float*)d_in[21];
  const float* o2_w = (const float*)d_in[22];
  const float* o2_b = (const float*)d_in[23];
  const float* o3_w = (const float*)d_in[24];
  const float* o3_b = (const float*)d_in[25];

  char* ws = (char*)d_ws;
  __bf16* wf = (__bf16*)(ws + WS_WF);
  __bf16* rra = (__bf16*)(ws + WS_RRA);
  float* tnode = (float*)(ws + WS_TN);
  float* g_agg = (float*)(ws + WS_AGG);
  __bf16* partb = (__bf16*)(ws + WS_PB);

  const int mode = (ws_size >= WS_NEED1) ? 1 : 0;

  prep_all<<<1239, 256, 0, stream>>>(mf2_w, at1_w1, at1_w2, mf1_w, mf1_b, rel_rec,
                                     at5_w1, at5_w2, o1_w, o2_w, o3_w, wf, rra, tnode);

  if (mode == 1) {
    hipFuncSetAttribute((const void*)edge_kernel<1>,
                        hipFuncAttributeMaxDynamicSharedMemorySize, LDS_EDGE_BYTES);
    edge_kernel<1><<<BT * 4, 1024, LDS_EDGE_BYTES, stream>>>(
        x, rel_rec, rel_send, rel_type, mf2_b, at1_b1, at1_b2,
        at1_g, at1_be, wf, rra, g_agg, partb);
    node_kernel<1><<<512, 256, 0, stream>>>(g_agg, partb, x, tnode, tnode + 67600,
                                            tnode + 135200, tnode + 201760, tnode + 267296,
                                            at5_b1, at5_b2, at5_g, at5_be,
                                            o1_b, o2_b, o3_b, (float*)d_out);
  } else {
    hipMemsetAsync(g_agg, 0, (size_t)BT * Nn * Hh * 4, stream);
    hipFuncSetAttribute((const void*)edge_kernel<0>,
                        hipFuncAttributeMaxDynamicSharedMemorySize, LDS_EDGE_BYTES);
    edge_kernel<0><<<BT * 4, 1024, LDS_EDGE_BYTES, stream>>>(
        x, rel_rec, rel_send, rel_type, mf2_b, at1_b1, at1_b2,
        at1_g, at1_be, wf, rra, g_agg, partb);
    node_kernel<0><<<512, 256, 0, stream>>>(g_agg, partb, x, tnode, tnode + 67600,
                                            tnode + 135200, tnode + 201760, tnode + 267296,
                                            at5_b1, at5_b2, at5_g, at5_be,
                                            o1_b, o2_b, o3_b, (float*)d_out);
  }
}

// Round 15
// 283.676 us; speedup vs baseline: 1.6155x; 1.0262x over previous
//
#include <hip/hip_runtime.h>
#include <hip/hip_bf16.h>
#include <math.h>

typedef __bf16 bf16x8 __attribute__((ext_vector_type(8)));
typedef __bf16 bf16x4 __attribute__((ext_vector_type(4)));
typedef float f32x4 __attribute__((ext_vector_type(4)));

#define MFMA16(a,b,c) __builtin_amdgcn_mfma_f32_16x16x32_bf16(a,b,c,0,0,0)

static constexpr int Nn = 48, Hh = 256;
static constexpr int Ee = 2256, BT = 64;
static constexpr int ETILE = 64, NTILES = 36;          // 36*64 = 2304 >= 2256
static constexpr float BN_RS = 0.9999950000374998f;    // 1/sqrt(1+1e-5)

// ---- ws layout (bytes) ----
static constexpr size_t WS_WF  = 0;         // 4 mats frag-linear + mf1 frags: 557056
static constexpr size_t WS_RRA = 557056;    // 36*2*3*64*8 bf16 = 221184
static constexpr size_t WS_TN  = 778240;    // 268320 f32 = 1073280
static constexpr size_t WS_AGG = 1851520;   // g_agg [64][48][256] f32 = 3145728 (MODE0)
static constexpr size_t WS_PB  = 4997248;   // bf16 partials [256][48][256] = 6291456 (MODE1)
static constexpr size_t WS_NEED1 = WS_PB + 6291456;  // 11288704

// ---- LDS layout (bytes), total 143616; 1024 threads, 1 block/CU ----
static constexpr int LDS_ACT = 0;        // [64][512B] swizzled act
static constexpr int LDS_ALM = 32768;    // [64][512B] all_msgs act, then h_edges B-frags
static constexpr int LDS_WSG = 65536;    // 2 x 32KB ring of weight chunks (wave-private rows)
static constexpr int LDS_PMA = 131072;   // [64][80B] pre_msg bf16 K=32-padded (k=8 const 1.0); 80B row de-aliases banks
static constexpr int LDS_RT  = 136192;   // [64][2] f32
static constexpr int LDS_BS  = 136704;   // 1536 f32 biases
static constexpr int LDS_XS  = 142848;   // 192 f32
static constexpr int LDS_EDGE_BYTES = 143616;

__device__ __forceinline__ float eluf(float v) { return v > 0.f ? v : __expf(v) - 1.f; }

typedef __attribute__((address_space(1))) const unsigned int as1_uint;
typedef __attribute__((address_space(3))) unsigned int as3_uint;
__device__ __forceinline__ void gload16(const void* g, void* l) {
  __builtin_amdgcn_global_load_lds((as1_uint*)g, (as3_uint*)l, 16, 0, 0);
}

__device__ __forceinline__ int aoff(int e, int colbyte) {
  return e * 512 + (colbyte ^ ((e & 7) << 4));
}

// lgkm-only barrier: LDS writes visible, DMA (vmcnt) stays in flight (T4).
#define LBAR() do { asm volatile("s_waitcnt lgkmcnt(0)" ::: "memory"); \
  __builtin_amdgcn_s_barrier(); __builtin_amdgcn_sched_barrier(0); } while (0)
// per-wave counted DMA wait: oldest chunk (2 loads) landed, 2 newer stay in flight.
#define VWAIT2() do { asm volatile("s_waitcnt vmcnt(2)" ::: "memory"); \
  __builtin_amdgcn_sched_barrier(0); } while (0)

// wave wv stages ONLY its own B rows {wv, wv+16} of a 32KB chunk (2KB via 2 DMA).
// WAVE-PRIVATE: these rows are read only by wave wv (round-14's shared-row
// variant raced: a sibling 2 chunks ahead overwrote unread ring data).
__device__ __forceinline__ void issueW(const char* chunkSrc, char* wsgbuf, int wv, int lane) {
  gload16(chunkSrc + wv * 1024 + lane * 16, wsgbuf + wv * 1024);
  gload16(chunkSrc + (16 + wv) * 1024 + lane * 16, wsgbuf + (16 + wv) * 1024);
}

// K=256 GEMM, 16-wave 1Mx16N split, wave-private software-pipelined weight DMA.
// Invariant on entry: this wave's chunks 0,1 of wmat already issued (in order),
// newest outstanding. Iterations 2,3 pre-issue nextw's chunks 0,1. NO barriers.
__device__ __forceinline__ void gemmK(char* smem, const char* wmat, const char* nextw,
                                      int abase, int lane, int wv, f32x4 acc[4]) {
  char* wsg = smem + LDS_WSG;
  const int kgb = (lane >> 4) * 16;
  const int c16 = lane & 15;
#pragma unroll
  for (int c = 0; c < 4; ++c) {
    VWAIT2();  // chunk c landed (this wave's rows)
#pragma unroll
    for (int ks = 0; ks < 2; ++ks) {
      const int kt = c * 2 + ks;
      bf16x8 bfr = *(const bf16x8*)(wsg + (c & 1) * 32768 + ((ks * 16 + wv) * 64 + lane) * 16);
#pragma unroll
      for (int mt = 0; mt < 4; ++mt) {
        int r = mt * 16 + c16;
        bf16x8 af = *(const bf16x8*)(smem + abase + r * 512 + ((kt * 64 + kgb) ^ ((r & 7) << 4)));
        acc[mt] = MFMA16(af, bfr, acc[mt]);
      }
    }
    __builtin_amdgcn_sched_barrier(0);  // keep re-issue below the ds_reads above
    const char* src = (c < 2) ? (wmat + (c + 2) * 32768) : (nextw + (c - 2) * 32768);
    issueW(src, wsg + (c & 1) * 32768, wv, lane);
  }
}

template<int MODE>
__global__ __launch_bounds__(1024)
void edge_kernel(const float* __restrict__ x, const float* __restrict__ rel_rec,
                 const float* __restrict__ rel_send, const float* __restrict__ rel_type,
                 const float* __restrict__ mf2_b, const float* __restrict__ at1_b1,
                 const float* __restrict__ at1_b2, const float* __restrict__ at1_g,
                 const float* __restrict__ at1_be, const __bf16* __restrict__ wf,
                 const __bf16* __restrict__ rra, float* __restrict__ g_agg,
                 __bf16* __restrict__ partb) {
  extern __shared__ char smem[];
  float* xs = (float*)(smem + LDS_XS);
  float* rt = (float*)(smem + LDS_RT);
  float* bs = (float*)(smem + LDS_BS);
  const char* wfb = (const char*)wf;

  const int tid = threadIdx.x;
  const int lane = tid & 63;
  const int wv = tid >> 6;                // 0..15
  const int lg = lane >> 4;
  const int col16 = lane & 15;
  const int slice = blockIdx.x >> 2;
  const int split = blockIdx.x & 3;
  const int t_begin = split * 9;

  // start the cross-GEMM DMA pipeline: mf2_0 chunks 0,1 (this wave's rows)
  issueW(wfb, smem + LDS_WSG, wv, lane);
  issueW(wfb + 32768, smem + LDS_WSG + 32768, wv, lane);

  // block-start preloads: xs, bias table, PMA zero+ones
  if (tid < Nn * 4) xs[tid] = x[slice * Nn * 4 + tid];
#pragma unroll
  for (int i = 0; i < 2; ++i) {
    int t = i * 1024 + tid;
    if (t < 1536) {
      int which = t >> 8, o = t & 255;
      float v;
      switch (which) {
        case 0: v = mf2_b[o]; break;
        case 1: v = mf2_b[256 + o]; break;
        case 2: v = at1_b1[o]; break;
        case 3: v = at1_b2[o]; break;
        case 4: v = at1_g[o] * BN_RS; break;
        default: v = at1_be[o]; break;
      }
      bs[t] = v;
    }
  }
  // PMA: [64][80B] rows; zeros with bf16 1.0 at k=8 (byte 16 -> uint idx%20==4)
#pragma unroll
  for (int t = tid; t < 1280; t += 1024)
    ((unsigned int*)(smem + LDS_PMA))[t] = ((t % 20) == 4) ? 0x00003f80u : 0u;

  f32x4 ag[3];
#pragma unroll
  for (int a = 0; a < 3; ++a) ag[a] = (f32x4){0.f, 0.f, 0.f, 0.f};
  LBAR();

  for (int tt = 0; tt < 9; ++tt) {
    const int tile = t_begin + tt;
    const int e0 = tile * ETILE;
    const int ne = (Ee - e0 < ETILE) ? (Ee - e0) : ETILE;

    if (tid < ETILE * 2) {
      int e = tid >> 1, i2 = tid & 1;
      rt[tid] = (e < ne) ? rel_type[((size_t)slice * Ee + e0 + e) * 2 + i2] : 0.f;
    }
    if (tid < 512) {
      int c = tid >> 6, e = tid & 63;
      float s = 0.f;
      if (e < ne) {
        const float* rel = ((c < 4) ? rel_send : rel_rec) + (size_t)(e0 + e) * Nn;
        int f = c & 3;
#pragma unroll
        for (int n = 0; n < Nn; ++n) s += rel[n] * xs[n * 4 + f];
      }
      *(__bf16*)(smem + LDS_PMA + e * 80 + c * 2) = (__bf16)s;
    }
    LBAR();  // B1: PMA + rt visible

#pragma unroll 1
    for (int ty = 0; ty < 2; ++ty) {
      {
        // fc1: A = PMA [64][32] (bias folded at k=8), B = mf1 frags from global
        const char* src = wfb + 524288 + ty * 16384 + ((size_t)(wv * 64 + lane)) * 16;
        bf16x8 wb = *(const bf16x8*)(src);
        f32x4 fa[4];
#pragma unroll
        for (int mt = 0; mt < 4; ++mt) fa[mt] = (f32x4){0.f, 0.f, 0.f, 0.f};
#pragma unroll
        for (int mt = 0; mt < 4; ++mt) {
          bf16x8 af = *(const bf16x8*)(smem + LDS_PMA + (mt * 16 + col16) * 80 + lg * 16);
          fa[mt] = MFMA16(af, wb, fa[mt]);
        }
        const int cb = (wv * 16 + col16) * 2;
#pragma unroll
        for (int mt = 0; mt < 4; ++mt)
#pragma unroll
          for (int r = 0; r < 4; ++r) {
            int e = mt * 16 + lg * 4 + r;
            *(__bf16*)(smem + LDS_ACT + aoff(e, cb)) = (__bf16)fmaxf(fa[mt][r], 0.f);
          }
      }
      LBAR();  // ACT visible to all waves

      f32x4 acc[4];
#pragma unroll
      for (int mt = 0; mt < 4; ++mt) acc[mt] = (f32x4){0.f, 0.f, 0.f, 0.f};
      const char* wm = wfb + (size_t)ty * 131072;
      const char* nx = wfb + (size_t)(ty + 1) * 131072;  // mf2_1 then at1_w1
      gemmK(smem, wm, nx, LDS_ACT, lane, wv, acc);
      const float bbv = bs[ty * 256 + wv * 16 + col16];
      const int cb = (wv * 16 + col16) * 2;
#pragma unroll
      for (int mt = 0; mt < 4; ++mt) {
#pragma unroll
        for (int r = 0; r < 4; ++r) {
          int e = mt * 16 + lg * 4 + r;
          float v = fmaxf(acc[mt][r] + bbv, 0.f) * rt[e * 2 + ty];
          __bf16* p = (__bf16*)(smem + LDS_ALM + aoff(e, cb));
          if (ty == 1) v += (float)*p;  // own patch: same thread wrote it at ty=0
          *p = (__bf16)v;
        }
      }
      LBAR();  // epilogue done: ACT free for next fc1 / ALM visible for at1_l1
    }

    // at1_l1: ALM @ W -> elu -> ACT
    {
      f32x4 acc[4];
#pragma unroll
      for (int mt = 0; mt < 4; ++mt) acc[mt] = (f32x4){0.f, 0.f, 0.f, 0.f};
      gemmK(smem, wfb + (size_t)2 * 131072, wfb + (size_t)3 * 131072, LDS_ALM, lane, wv, acc);
      const float bbv = bs[512 + wv * 16 + col16];
      const int cb = (wv * 16 + col16) * 2;
#pragma unroll
      for (int mt = 0; mt < 4; ++mt)
#pragma unroll
        for (int r = 0; r < 4; ++r) {
          int e = mt * 16 + lg * 4 + r;
          *(__bf16*)(smem + LDS_ACT + aoff(e, cb)) = (__bf16)eluf(acc[mt][r] + bbv);
        }
    }
    LBAR();  // ACT(elu) visible; all waves out of l1-gemm

    // at1_l2: ACT @ W -> elu*sc+be -> h_edges B-frags in ALM
    {
      f32x4 acc[4];
#pragma unroll
      for (int mt = 0; mt < 4; ++mt) acc[mt] = (f32x4){0.f, 0.f, 0.f, 0.f};
      gemmK(smem, wfb + (size_t)3 * 131072, wfb, LDS_ACT, lane, wv, acc);  // next: mf2_0 (next tile)
      const int col = wv * 16 + col16;
      const float b_ = bs[768 + col], s1 = bs[1024 + col], s2 = bs[1280 + col];
      const int j0 = (lg & 1) * 4;
#pragma unroll
      for (int mt = 0; mt < 4; ++mt) {
        const int khalf = mt >> 1;
        const int lane2 = col16 | ((((mt & 1) * 2) + (lg >> 1)) << 4);
        bf16x4 pk;
#pragma unroll
        for (int r = 0; r < 4; ++r)
          pk[r] = (__bf16)(eluf(acc[mt][r] + b_) * s1 + s2);
        int addr = (((khalf * 16 + wv) * 64 + lane2) * 8 + j0) * 2;
        *(bf16x4*)(smem + LDS_ALM + addr) = pk;
      }
    }
    LBAR();  // B-frags visible; all waves out of l2-gemm

    // agg GEMM: ag += rel_rec[tile]^T @ h_edges  (M=48, N=256, K=64)
    const bf16x8* rraw = (const bf16x8*)rra + (size_t)tile * 384;
#pragma unroll
    for (int kt2 = 0; kt2 < 2; ++kt2) {
      bf16x8 b = *(const bf16x8*)(smem + LDS_ALM + ((kt2 * 16 + wv) * 64 + lane) * 16);
#pragma unroll
      for (int mt2 = 0; mt2 < 3; ++mt2) {
        bf16x8 a = rraw[(kt2 * 3 + mt2) * 64 + lane];
        ag[mt2] = MFMA16(a, b, ag[mt2]);
      }
    }
    // next tile's PMA/rt writes are disjoint from agg's reads; B1 gates fc1
  }

  if (MODE == 1) {
    __bf16* dst = partb + (size_t)blockIdx.x * Nn * Hh;
    const int h = wv * 16 + col16;
#pragma unroll
    for (int mt2 = 0; mt2 < 3; ++mt2)
#pragma unroll
      for (int r = 0; r < 4; ++r) {
        int n = mt2 * 16 + lg * 4 + r;
        dst[n * Hh + h] = (__bf16)ag[mt2][r];
      }
  } else {
    float* dst = g_agg + (size_t)slice * Nn * Hh;
    const int h = wv * 16 + col16;
#pragma unroll
    for (int mt2 = 0; mt2 < 3; ++mt2)
#pragma unroll
      for (int r = 0; r < 4; ++r) {
        int n = mt2 * 16 + lg * 4 + r;
        atomicAdd(dst + n * Hh + h, ag[mt2][r]);
      }
  }
}

// merged prep: blocks [0,128) frag, [128,136) mf1, [136,190) rra, [190,1239) node
__global__ void prep_all(const float* __restrict__ mf2_w, const float* __restrict__ at1_w1,
                         const float* __restrict__ at1_w2, const float* __restrict__ mf1_w,
                         const float* __restrict__ mf1_b, const float* __restrict__ rel_rec,
                         const float* __restrict__ at5_w1, const float* __restrict__ at5_w2,
                         const float* __restrict__ o1_w, const float* __restrict__ o2_w,
                         const float* __restrict__ o3_w,
                         __bf16* __restrict__ wfdst, __bf16* __restrict__ rra,
                         float* __restrict__ tn) {
  int b = blockIdx.x;
  if (b < 128) {
    int id = b * 256 + threadIdx.x;  // 32768
    int mat = id >> 13, r = id & 8191;
    int kt = r >> 10, q = r & 1023, nt = q >> 6, l = q & 63;
    int row = nt * 16 + (l & 15), col = kt * 32 + (l >> 4) * 8;
    const float* src = (mat == 0) ? mf2_w : (mat == 1) ? (mf2_w + 65536)
                     : (mat == 2) ? at1_w1 : at1_w2;
    const float* p = src + row * 256 + col;
    __bf16* d = wfdst + (size_t)mat * 65536 + ((size_t)(kt * 16 + nt) * 64 + l) * 8;
#pragma unroll
    for (int j = 0; j < 8; ++j) d[j] = (__bf16)p[j];
    return;
  }
  if (b < 136) {
    int id = (b - 128) * 256 + threadIdx.x;  // 2048
    int ty = id >> 10, q = id & 1023, ntg = q >> 6, l = q & 63;
    int col = ntg * 16 + (l & 15);
    int k0 = (l >> 4) * 8;
    bf16x8 v;
#pragma unroll
    for (int j = 0; j < 8; ++j) {
      int k = k0 + j;
      float xv = (k < 8) ? mf1_w[ty * 2048 + col * 8 + k]
               : (k == 8) ? mf1_b[ty * 256 + col] : 0.f;
      v[j] = (__bf16)xv;
    }
    ((bf16x8*)(wfdst + 262144))[id] = v;
    return;
  }
  if (b < 190) {
    int id = (b - 136) * 256 + threadIdx.x;  // 13824
    if (id >= 13824) return;
    int tile = id / 384, r = id % 384;
    int kt2 = r / 192, r2 = r % 192, mt2 = r2 >> 6, l = r2 & 63;
    int ebase = tile * 64 + kt2 * 32 + (l >> 4) * 8;
    int n = mt2 * 16 + (l & 15);
    bf16x8 v;
#pragma unroll
    for (int j = 0; j < 8; ++j) {
      int e = ebase + j;
      v[j] = (__bf16)((e < Ee) ? rel_rec[(size_t)e * Nn + n] : 0.f);
    }
    ((bf16x8*)rra)[id] = v;
    return;
  }
  int id = (b - 190) * 256 + threadIdx.x;
  float* T1 = tn;
  float* T2 = T1 + 67600;
  float* To1 = T2 + 67600;
  float* To2 = To1 + 66560;
  float* To3 = To2 + 65536;
  if (id < 67600) { int o = id % 260, k = id / 260; T1[k * 260 + o] = at5_w1[o * 260 + k]; return; }
  id -= 67600;
  if (id < 67600) { int o = id % 260, k = id / 260; T2[k * 260 + o] = at5_w2[o * 260 + k]; return; }
  id -= 67600;
  if (id < 66560) { int o = id & 255, k = id >> 8; To1[k * 256 + o] = o1_w[o * 260 + k]; return; }
  id -= 66560;
  if (id < 65536) { int o = id & 255, k = id >> 8; To2[k * 256 + o] = o2_w[o * 256 + k]; return; }
  id -= 65536;
  if (id < 1024) { int f = id & 3, k = id >> 2; To3[k * 4 + f] = o3_w[f * 256 + k]; }
}

// 512 blocks x 6 node-rows each; LDS reads quad-vectorized (b128)
template<int MODE>
__global__ __launch_bounds__(256, 4)
void node_kernel(const float* __restrict__ g_agg, const __bf16* __restrict__ partb,
                 const float* __restrict__ x,
                 const float* __restrict__ T1, const float* __restrict__ T2,
                 const float* __restrict__ To1, const float* __restrict__ To2,
                 const float* __restrict__ To3, const float* __restrict__ at5_b1,
                 const float* __restrict__ at5_b2, const float* __restrict__ at5_g,
                 const float* __restrict__ at5_be, const float* __restrict__ o1_b,
                 const float* __restrict__ o2_b, const float* __restrict__ o3_b,
                 float* __restrict__ out) {
  __shared__ __align__(16) float bufA[6 * 264], bufB[6 * 264];
  __shared__ float xres[6 * 4];
  const int tid = threadIdx.x;
  const int slice = blockIdx.x >> 3, rg = blockIdx.x & 7;
  const int n0 = rg * 6;
  for (int t = tid; t < 6 * 256; t += 256) {
    int r = t >> 8, h = t & 255;
    float s;
    if (MODE == 1) {
      s = 0.f;
#pragma unroll
      for (int sp = 0; sp < 4; ++sp)
        s += (float)partb[((((size_t)slice * 4 + sp) * Nn) + n0 + r) * Hh + h];
    } else {
      s = g_agg[(size_t)slice * 12288 + (size_t)(n0 + r) * 256 + h];
    }
    bufA[r * 264 + h] = s;
  }
  if (tid < 24) {
    int r = tid >> 2, f = tid & 3;
    float v = x[(size_t)slice * 192 + (n0 + r) * 4 + f];
    bufA[r * 264 + 256 + f] = v;
    xres[tid] = v;
  }
  __syncthreads();

  auto layer = [&](const float* WT, const float* bsrc, const float* in, float* outb,
                   int K, int O, int act, const float* gsc, const float* gbe) {
    for (int o = tid; o < O; o += 256) {
      float a[6];
      float bb = bsrc[o];
#pragma unroll
      for (int r = 0; r < 6; ++r) a[r] = bb;
      for (int k = 0; k < K; k += 4) {
        float w0 = WT[k * O + o], w1 = WT[(k + 1) * O + o];
        float w2 = WT[(k + 2) * O + o], w3 = WT[(k + 3) * O + o];
#pragma unroll
        for (int r = 0; r < 6; ++r) {
          f32x4 iv = *(const f32x4*)(in + r * 264 + k);
          a[r] = fmaf(iv[0], w0, a[r]);
          a[r] = fmaf(iv[1], w1, a[r]);
          a[r] = fmaf(iv[2], w2, a[r]);
          a[r] = fmaf(iv[3], w3, a[r]);
        }
      }
      float scv = 1.f, bev = 0.f;
      if (act == 2) { scv = gsc[o] * BN_RS; bev = gbe[o]; }
#pragma unroll
      for (int r = 0; r < 6; ++r) {
        float v = a[r];
        v = (act == 0) ? fmaxf(v, 0.f) : eluf(v);
        if (act == 2) v = v * scv + bev;
        outb[r * 264 + o] = v;
      }
    }
    __syncthreads();
  };

  layer(T1, at5_b1, bufA, bufB, 260, 260, 1, nullptr, nullptr);
  layer(T2, at5_b2, bufB, bufA, 260, 260, 2, at5_g, at5_be);
  layer(To1, o1_b, bufA, bufB, 260, 256, 0, nullptr, nullptr);
  layer(To2, o2_b, bufB, bufA, 256, 256, 0, nullptr, nullptr);
  if (tid < 24) {
    int r = tid >> 2, f = tid & 3;
    float s = o3_b[f];
    for (int k = 0; k < 256; k += 4) {
      f32x4 iv = *(const f32x4*)(bufA + r * 264 + k);
      s = fmaf(iv[0], To3[k * 4 + f], s);
      s = fmaf(iv[1], To3[(k + 1) * 4 + f], s);
      s = fmaf(iv[2], To3[(k + 2) * 4 + f], s);
      s = fmaf(iv[3], To3[(k + 3) * 4 + f], s);
    }
    out[(size_t)slice * 192 + (n0 + r) * 4 + f] = xres[tid] + s;
  }
}

extern "C" void kernel_launch(void* const* d_in, const int* in_sizes, int n_in,
                              void* d_out, int out_size, void* d_ws, size_t ws_size,
                              hipStream_t stream) {
  const float* x = (const float*)d_in[0];
  const float* rel_rec = (const float*)d_in[1];
  const float* rel_send = (const float*)d_in[2];
  const float* rel_type = (const float*)d_in[3];
  const float* mf1_w = (const float*)d_in[4];
  const float* mf1_b = (const float*)d_in[5];
  const float* mf2_w = (const float*)d_in[6];
  const float* mf2_b = (const float*)d_in[7];
  const float* at1_w1 = (const float*)d_in[8];
  const float* at1_b1 = (const float*)d_in[9];
  const float* at1_w2 = (const float*)d_in[10];
  const float* at1_b2 = (const float*)d_in[11];
  const float* at1_g = (const float*)d_in[12];
  const float* at1_be = (const float*)d_in[13];
  const float* at5_w1 = (const float*)d_in[14];
  const float* at5_b1 = (const float*)d_in[15];
  const float* at5_w2 = (const float*)d_in[16];
  const float* at5_b2 = (const float*)d_in[17];
  const float* at5_g = (const float*)d_in[18];
  const float* at5_be = (const float*)d_in[19];
  const float* o1_w = (const float*)d_in[20];
  const float* o1_b = (const float*)d_in[21];
  const float* o2_w = (const float*)d_in[22];
  const float* o2_b = (const float*)d_in[23];
  const float* o3_w = (const float*)d_in[24];
  const float* o3_b = (const float*)d_in[25];

  char* ws = (char*)d_ws;
  __bf16* wf = (__bf16*)(ws + WS_WF);
  __bf16* rra = (__bf16*)(ws + WS_RRA);
  float* tnode = (float*)(ws + WS_TN);
  float* g_agg = (float*)(ws + WS_AGG);
  __bf16* partb = (__bf16*)(ws + WS_PB);

  const int mode = (ws_size >= WS_NEED1) ? 1 : 0;

  prep_all<<<1239, 256, 0, stream>>>(mf2_w, at1_w1, at1_w2, mf1_w, mf1_b, rel_rec,
                                     at5_w1, at5_w2, o1_w, o2_w, o3_w, wf, rra, tnode);

  if (mode == 1) {
    hipFuncSetAttribute((const void*)edge_kernel<1>,
                        hipFuncAttributeMaxDynamicSharedMemorySize, LDS_EDGE_BYTES);
    edge_kernel<1><<<BT * 4, 1024, LDS_EDGE_BYTES, stream>>>(
        x, rel_rec, rel_send, rel_type, mf2_b, at1_b1, at1_b2,
        at1_g, at1_be, wf, rra, g_agg, partb);
    node_kernel<1><<<512, 256, 0, stream>>>(g_agg, partb, x, tnode, tnode + 67600,
                                            tnode + 135200, tnode + 201760, tnode + 267296,
                                            at5_b1, at5_b2, at5_g, at5_be,
                                            o1_b, o2_b, o3_b, (float*)d_out);
  } else {
    hipMemsetAsync(g_agg, 0, (size_t)BT * Nn * Hh * 4, stream);
    hipFuncSetAttribute((const void*)edge_kernel<0>,
                        hipFuncAttributeMaxDynamicSharedMemorySize, LDS_EDGE_BYTES);
    edge_kernel<0><<<BT * 4, 1024, LDS_EDGE_BYTES, stream>>>(
        x, rel_rec, rel_send, rel_type, mf2_b, at1_b1, at1_b2,
        at1_g, at1_be, wf, rra, g_agg, partb);
    node_kernel<0><<<512, 256, 0, stream>>>(g_agg, partb, x, tnode, tnode + 67600,
                                            tnode + 135200, tnode + 201760, tnode + 267296,
                                            at5_b1, at5_b2, at5_g, at5_be,
                                            o1_b, o2_b, o3_b, (float*)d_out);
  }
}